// Round 1
// baseline (622.307 us; speedup 1.0000x reference)
//
#include <hip/hip_runtime.h>
#include <cstddef>

#define CC 128
#define NH 8
#define HD 16
#define DDIM 31
#define HWW 1024
#define TOK 31744   // DDIM * HWW
#define SCALE2 0.0625f   // (HD^-0.5)^2 — both operands of QK^T are pre-scaled in the ref

// ---------------------------------------------------------------------------
// Kernel 1: Q projection.  q[t][c] = sum_ci x[ci][t] * Wq[ci][c] + bq[c]
// x is [C][T] (natural layout of (B,C,D,H,W)); output token-major [T][C].
// Block: 128 tokens x 64 out-channels; thread: 8 tokens x 4 channels.
// ---------------------------------------------------------------------------
__global__ __launch_bounds__(256) void qproj_kernel(
    const float* __restrict__ x, const float* __restrict__ Wq,
    const float* __restrict__ bq, float* __restrict__ qout)
{
    __shared__ __align__(16) float wts[CC][64];   // 32 KB  [ci][co-co0]
    __shared__ __align__(16) float xs[8][128];    // 4 KB   [ci-chunk][t]
    const int tid = threadIdx.x;
    const int t0  = blockIdx.x * 128;
    const int co0 = blockIdx.y * 64;

    for (int i = tid; i < CC * 16; i += 256) {
        int k = i >> 4, q4 = i & 15;
        ((float4*)&wts[k][0])[q4] = *(const float4*)&Wq[k * CC + co0 + q4 * 4];
    }
    const int tg = tid >> 4;   // 16 groups of 8 tokens
    const int cg = tid & 15;   // 16 groups of 4 channels
    float acc[8][4];
#pragma unroll
    for (int i = 0; i < 8; ++i)
#pragma unroll
        for (int j = 0; j < 4; ++j) acc[i][j] = 0.f;

    for (int c0 = 0; c0 < CC; c0 += 8) {
        __syncthreads();
        for (int i = tid; i < 1024; i += 256) {
            int r = i >> 7, t = i & 127;
            xs[r][t] = x[(size_t)(c0 + r) * TOK + t0 + t];
        }
        __syncthreads();
#pragma unroll
        for (int r = 0; r < 8; ++r) {
            float4 xa = *(const float4*)&xs[r][tg * 8];
            float4 xb = *(const float4*)&xs[r][tg * 8 + 4];
            float4 w  = *(const float4*)&wts[c0 + r][cg * 4];
            float xv[8] = {xa.x, xa.y, xa.z, xa.w, xb.x, xb.y, xb.z, xb.w};
            float wv[4] = {w.x, w.y, w.z, w.w};
#pragma unroll
            for (int i = 0; i < 8; ++i)
#pragma unroll
                for (int j = 0; j < 4; ++j) acc[i][j] += xv[i] * wv[j];
        }
    }
    float bv[4];
#pragma unroll
    for (int j = 0; j < 4; ++j) bv[j] = bq[co0 + cg * 4 + j];
#pragma unroll
    for (int i = 0; i < 8; ++i) {
        int t = t0 + tg * 8 + i;
        float4 o = {acc[i][0] + bv[0], acc[i][1] + bv[1],
                    acc[i][2] + bv[2], acc[i][3] + bv[3]};
        *(float4*)&qout[(size_t)t * CC + co0 + cg * 4] = o;
    }
}

// ---------------------------------------------------------------------------
// Kernel 2: spectral attention — sequences over d (L=31) per (h,w), 8 heads.
// In-place on q (block loads its entire slice to LDS before any write).
// One block per hw; thread = (head, l) for tid < 248.
// ---------------------------------------------------------------------------
__global__ __launch_bounds__(256) void attn_spec_kernel(float* __restrict__ q)
{
    __shared__ __align__(16) float qs[DDIM][CC];   // 15.9 KB
    const int hw  = blockIdx.x;
    const int tid = threadIdx.x;
    for (int i = tid; i < DDIM * 32; i += 256) {
        int d = i >> 5, c4 = i & 31;
        ((float4*)&qs[d][0])[c4] = *(const float4*)&q[((size_t)d * HWW + hw) * CC + c4 * 4];
    }
    __syncthreads();
    if (tid < NH * DDIM) {
        const int h = tid / DDIM;
        const int l = tid % DDIM;
        const int hc = h * HD;
        float qr[HD];
#pragma unroll
        for (int dd = 0; dd < HD; ++dd) qr[dd] = qs[l][hc + dd];
        float p[DDIM];
        float smax = -1e30f;
#pragma unroll
        for (int m = 0; m < DDIM; ++m) {
            float s = 0.f;
#pragma unroll
            for (int dd = 0; dd < HD; ++dd) s += qr[dd] * qs[m][hc + dd];
            s *= SCALE2;
            p[m] = s;
            smax = fmaxf(smax, s);
        }
        float ssum = 0.f;
#pragma unroll
        for (int m = 0; m < DDIM; ++m) { p[m] = __expf(p[m] - smax); ssum += p[m]; }
        float inv = 1.f / ssum;
        float o[HD];
#pragma unroll
        for (int dd = 0; dd < HD; ++dd) o[dd] = 0.f;
#pragma unroll
        for (int m = 0; m < DDIM; ++m) {
            float pm = p[m] * inv;
#pragma unroll
            for (int dd = 0; dd < HD; ++dd) o[dd] += pm * qs[m][hc + dd];
        }
#pragma unroll
        for (int q4 = 0; q4 < 4; ++q4) {
            float4 ov = {o[q4*4], o[q4*4+1], o[q4*4+2], o[q4*4+3]};
            *(float4*)&q[((size_t)l * HWW + hw) * CC + hc + q4 * 4] = ov;
        }
    }
}

// ---------------------------------------------------------------------------
// Kernel 3: spatial attention — sequences over hw (L=1024) per d, per head.
// One block per (d, head). Whole Q-slice (1024 x 16 fp32 = 64 KB) in LDS.
// Thread owns 4 rows, streams all 1024 keys. Scores are bounded (|s|<~2) so
// softmax runs without max subtraction (mathematically identical).
// In-place on q (disjoint byte ranges per block; loads complete before writes).
// ---------------------------------------------------------------------------
__global__ __launch_bounds__(256) void attn_spat_kernel(float* __restrict__ q)
{
    __shared__ __align__(16) float qs[HWW][HD];   // 64 KB
    const int d   = blockIdx.x;
    const int h   = blockIdx.y;
    const int tid = threadIdx.x;
    const size_t base = (size_t)d * HWW * CC + h * HD;
    for (int i = tid; i < HWW * 4; i += 256) {
        int row = i >> 2, q4 = i & 3;
        ((float4*)&qs[row][0])[q4] = *(const float4*)&q[base + (size_t)row * CC + q4 * 4];
    }
    __syncthreads();
    float qr[4][HD];
#pragma unroll
    for (int r = 0; r < 4; ++r)
#pragma unroll
        for (int dd = 0; dd < HD; ++dd) qr[r][dd] = qs[tid + r * 256][dd];
    float acc[4][HD];
#pragma unroll
    for (int r = 0; r < 4; ++r)
#pragma unroll
        for (int dd = 0; dd < HD; ++dd) acc[r][dd] = 0.f;
    float ssum[4] = {0.f, 0.f, 0.f, 0.f};

    for (int m = 0; m < HWW; ++m) {
        float4 qa = ((const float4*)&qs[m][0])[0];
        float4 qb = ((const float4*)&qs[m][0])[1];
        float4 qc = ((const float4*)&qs[m][0])[2];
        float4 qd = ((const float4*)&qs[m][0])[3];
        float qm[HD] = {qa.x,qa.y,qa.z,qa.w, qb.x,qb.y,qb.z,qb.w,
                        qc.x,qc.y,qc.z,qc.w, qd.x,qd.y,qd.z,qd.w};
#pragma unroll
        for (int r = 0; r < 4; ++r) {
            float s = 0.f;
#pragma unroll
            for (int dd = 0; dd < HD; ++dd) s += qr[r][dd] * qm[dd];
            float pe = __expf(s * SCALE2);
            ssum[r] += pe;
#pragma unroll
            for (int dd = 0; dd < HD; ++dd) acc[r][dd] += pe * qm[dd];
        }
    }
#pragma unroll
    for (int r = 0; r < 4; ++r) {
        float inv = 1.f / ssum[r];
        int row = tid + r * 256;
#pragma unroll
        for (int q4 = 0; q4 < 4; ++q4) {
            float4 ov = {acc[r][q4*4]*inv, acc[r][q4*4+1]*inv,
                         acc[r][q4*4+2]*inv, acc[r][q4*4+3]*inv};
            *(float4*)&q[base + (size_t)row * CC + q4 * 4] = ov;
        }
    }
}

// ---------------------------------------------------------------------------
// Kernel 4: column sums over tokens (for the gate's global-average pool).
// ---------------------------------------------------------------------------
__global__ __launch_bounds__(128) void colsum_kernel(
    const float* __restrict__ a, float* __restrict__ sums)
{
    const int tid = threadIdx.x;
    const float* p = a + (size_t)blockIdx.x * HWW * CC;
    float s = 0.f;
    for (int r = 0; r < HWW; ++r) s += p[(size_t)r * CC + tid];
    atomicAdd(&sums[tid], s);
}

// ---------------------------------------------------------------------------
// Kernel 5: gate. mean -> project through Wp (exact, by linearity) -> Wg -> sigmoid.
// ---------------------------------------------------------------------------
__global__ __launch_bounds__(128) void gate_kernel(
    const float* __restrict__ sums,
    const float* __restrict__ Wp1, const float* __restrict__ bp1,
    const float* __restrict__ Wp2, const float* __restrict__ bp2,
    const float* __restrict__ Wg,  const float* __restrict__ bg,
    float* __restrict__ gate)
{
    __shared__ float mean1[CC], mean2[CC], gi[2 * CC];
    const int c = threadIdx.x;
    const float invT = 1.f / (float)TOK;
    mean1[c] = sums[c] * invT;
    mean2[c] = sums[CC + c] * invT;
    __syncthreads();
    float a1 = bp1[c], a2 = bp2[c];
    for (int k = 0; k < CC; ++k) {
        a1 += mean1[k] * Wp1[k * CC + c];
        a2 += mean2[k] * Wp2[k * CC + c];
    }
    gi[c] = a1; gi[CC + c] = a2;
    __syncthreads();
    float g = bg[c];
    for (int j = 0; j < 2 * CC; ++j) g += gi[j] * Wg[j * CC + c];
    gate[c] = 1.f / (1.f + __expf(-g));
}

// ---------------------------------------------------------------------------
// Kernel 6: output projection + gated combine, one branch per launch.
// mode 0: out[c][t]  = g[c]     * (a@Wp + bp)[t][c]
// mode 1: out[c][t] += (1-g[c]) * (a@Wp + bp)[t][c]
// ---------------------------------------------------------------------------
__global__ __launch_bounds__(256) void proj_kernel(
    const float* __restrict__ a, const float* __restrict__ Wp,
    const float* __restrict__ bp, const float* __restrict__ gate,
    const int mode, float* __restrict__ out)
{
    __shared__ __align__(16) float wsm[CC][64];   // 32 KB [k][co-co0]
    __shared__ __align__(16) float as[8][132];    // k-chunk x tokens (+pad)
    const int tid = threadIdx.x;
    const int t0  = blockIdx.x * 128;
    const int co0 = blockIdx.y * 64;
    for (int i = tid; i < CC * 16; i += 256) {
        int k = i >> 4, q4 = i & 15;
        ((float4*)&wsm[k][0])[q4] = *(const float4*)&Wp[k * CC + co0 + q4 * 4];
    }
    const int tg = tid >> 4;
    const int cg = tid & 15;
    float acc[8][4];
#pragma unroll
    for (int i = 0; i < 8; ++i)
#pragma unroll
        for (int j = 0; j < 4; ++j) acc[i][j] = 0.f;

    for (int k0 = 0; k0 < CC; k0 += 8) {
        __syncthreads();
        for (int i = tid; i < 1024; i += 256) {
            int t = i >> 3, k = i & 7;
            as[k][t] = a[(size_t)(t0 + t) * CC + k0 + k];
        }
        __syncthreads();
#pragma unroll
        for (int k = 0; k < 8; ++k) {
            float4 xa = *(const float4*)&as[k][tg * 8];
            float4 xb = *(const float4*)&as[k][tg * 8 + 4];
            float4 w  = *(const float4*)&wsm[k0 + k][cg * 4];
            float xv[8] = {xa.x, xa.y, xa.z, xa.w, xb.x, xb.y, xb.z, xb.w};
            float wv[4] = {w.x, w.y, w.z, w.w};
#pragma unroll
            for (int i = 0; i < 8; ++i)
#pragma unroll
                for (int j = 0; j < 4; ++j) acc[i][j] += xv[i] * wv[j];
        }
    }
#pragma unroll
    for (int j = 0; j < 4; ++j) {
        int co = co0 + cg * 4 + j;
        float g = gate[co];
        if (mode) g = 1.f - g;
        float b = bp[co];
        float v[8];
#pragma unroll
        for (int i = 0; i < 8; ++i) v[i] = g * (acc[i][j] + b);
        if (mode) {
#pragma unroll
            for (int i = 0; i < 8; ++i) v[i] += out[(size_t)co * TOK + t0 + tg * 8 + i];
        }
        float4 o1 = {v[0], v[1], v[2], v[3]};
        float4 o2 = {v[4], v[5], v[6], v[7]};
        *(float4*)&out[(size_t)co * TOK + t0 + tg * 8]     = o1;
        *(float4*)&out[(size_t)co * TOK + t0 + tg * 8 + 4] = o2;
    }
}

extern "C" void kernel_launch(void* const* d_in, const int* in_sizes, int n_in,
                              void* d_out, int out_size, void* d_ws, size_t ws_size,
                              hipStream_t stream)
{
    const float* x   = (const float*)d_in[0];
    const float* Wq1 = (const float*)d_in[1];
    const float* bq1 = (const float*)d_in[2];
    const float* Wp1 = (const float*)d_in[3];
    const float* bp1 = (const float*)d_in[4];
    const float* Wq2 = (const float*)d_in[5];
    const float* bq2 = (const float*)d_in[6];
    const float* Wp2 = (const float*)d_in[7];
    const float* bp2 = (const float*)d_in[8];
    const float* Wg  = (const float*)d_in[9];
    const float* bg  = (const float*)d_in[10];
    float* out = (float*)d_out;

    float* q1   = (float*)d_ws;                 // spec q / attn-out (in-place), 16.25 MB
    float* q2   = q1 + (size_t)TOK * CC;        // spat q / attn-out (in-place), 16.25 MB
    float* sums = q2 + (size_t)TOK * CC;        // 256 floats
    float* gate = sums + 2 * CC;                // 128 floats

    qproj_kernel<<<dim3(248, 2), 256, 0, stream>>>(x, Wq1, bq1, q1);
    qproj_kernel<<<dim3(248, 2), 256, 0, stream>>>(x, Wq2, bq2, q2);
    attn_spec_kernel<<<dim3(1024), 256, 0, stream>>>(q1);
    attn_spat_kernel<<<dim3(DDIM, NH), 256, 0, stream>>>(q2);
    hipMemsetAsync(sums, 0, 2 * CC * sizeof(float), stream);
    colsum_kernel<<<dim3(DDIM), 128, 0, stream>>>(q1, sums);
    colsum_kernel<<<dim3(DDIM), 128, 0, stream>>>(q2, sums + CC);
    gate_kernel<<<1, 128, 0, stream>>>(sums, Wp1, bp1, Wp2, bp2, Wg, bg, gate);
    proj_kernel<<<dim3(248, 2), 256, 0, stream>>>(q1, Wp1, bp1, gate, 0, out);
    proj_kernel<<<dim3(248, 2), 256, 0, stream>>>(q2, Wp2, bp2, gate, 1, out);
}

// Round 2
// 535.055 us; speedup vs baseline: 1.1631x; 1.1631x over previous
//
#include <hip/hip_runtime.h>
#include <cstddef>

#define CC 128
#define NH 8
#define HD 16
#define DDIM 31
#define HWW 1024
#define TOK 31744   // DDIM * HWW
#define SCALE2 0.0625f   // (HD^-0.5)^2 — both operands of QK^T are pre-scaled in the ref

// ---------------------------------------------------------------------------
// Kernel 1: Q projection.  q[t][c] = sum_ci x[ci][t] * Wq[ci][c] + bq[c]
// x is [C][T] (natural layout of (B,C,D,H,W)); output token-major [T][C].
// Block: 128 tokens x 64 out-channels; thread: 8 tokens x 4 channels.
// ---------------------------------------------------------------------------
__global__ __launch_bounds__(256) void qproj_kernel(
    const float* __restrict__ x, const float* __restrict__ Wq,
    const float* __restrict__ bq, float* __restrict__ qout)
{
    __shared__ __align__(16) float wts[CC][64];   // 32 KB  [ci][co-co0]
    __shared__ __align__(16) float xs[8][128];    // 4 KB   [ci-chunk][t]
    const int tid = threadIdx.x;
    const int t0  = blockIdx.x * 128;
    const int co0 = blockIdx.y * 64;

    for (int i = tid; i < CC * 16; i += 256) {
        int k = i >> 4, q4 = i & 15;
        ((float4*)&wts[k][0])[q4] = *(const float4*)&Wq[k * CC + co0 + q4 * 4];
    }
    const int tg = tid >> 4;   // 16 groups of 8 tokens
    const int cg = tid & 15;   // 16 groups of 4 channels
    float acc[8][4];
#pragma unroll
    for (int i = 0; i < 8; ++i)
#pragma unroll
        for (int j = 0; j < 4; ++j) acc[i][j] = 0.f;

    for (int c0 = 0; c0 < CC; c0 += 8) {
        __syncthreads();
        for (int i = tid; i < 1024; i += 256) {
            int r = i >> 7, t = i & 127;
            xs[r][t] = x[(size_t)(c0 + r) * TOK + t0 + t];
        }
        __syncthreads();
#pragma unroll
        for (int r = 0; r < 8; ++r) {
            float4 xa = *(const float4*)&xs[r][tg * 8];
            float4 xb = *(const float4*)&xs[r][tg * 8 + 4];
            float4 w  = *(const float4*)&wts[c0 + r][cg * 4];
            float xv[8] = {xa.x, xa.y, xa.z, xa.w, xb.x, xb.y, xb.z, xb.w};
            float wv[4] = {w.x, w.y, w.z, w.w};
#pragma unroll
            for (int i = 0; i < 8; ++i)
#pragma unroll
                for (int j = 0; j < 4; ++j) acc[i][j] += xv[i] * wv[j];
        }
    }
    float bv[4];
#pragma unroll
    for (int j = 0; j < 4; ++j) bv[j] = bq[co0 + cg * 4 + j];
#pragma unroll
    for (int i = 0; i < 8; ++i) {
        int t = t0 + tg * 8 + i;
        float4 o = {acc[i][0] + bv[0], acc[i][1] + bv[1],
                    acc[i][2] + bv[2], acc[i][3] + bv[3]};
        *(float4*)&qout[(size_t)t * CC + co0 + cg * 4] = o;
    }
}

// ---------------------------------------------------------------------------
// Kernel 2: spectral attention — sequences over d (L=31) per (h,w), 8 heads.
// In-place on q (block loads its entire slice to LDS before any write).
// One block per hw; thread = (head, l) for tid < 248.
// ---------------------------------------------------------------------------
__global__ __launch_bounds__(256) void attn_spec_kernel(float* __restrict__ q)
{
    __shared__ __align__(16) float qs[DDIM][CC];   // 15.9 KB
    const int hw  = blockIdx.x;
    const int tid = threadIdx.x;
    for (int i = tid; i < DDIM * 32; i += 256) {
        int d = i >> 5, c4 = i & 31;
        ((float4*)&qs[d][0])[c4] = *(const float4*)&q[((size_t)d * HWW + hw) * CC + c4 * 4];
    }
    __syncthreads();
    if (tid < NH * DDIM) {
        const int h = tid / DDIM;
        const int l = tid % DDIM;
        const int hc = h * HD;
        float qr[HD];
#pragma unroll
        for (int dd = 0; dd < HD; ++dd) qr[dd] = qs[l][hc + dd];
        float p[DDIM];
        float smax = -1e30f;
#pragma unroll
        for (int m = 0; m < DDIM; ++m) {
            float s = 0.f;
#pragma unroll
            for (int dd = 0; dd < HD; ++dd) s += qr[dd] * qs[m][hc + dd];
            s *= SCALE2;
            p[m] = s;
            smax = fmaxf(smax, s);
        }
        float ssum = 0.f;
#pragma unroll
        for (int m = 0; m < DDIM; ++m) { p[m] = __expf(p[m] - smax); ssum += p[m]; }
        float inv = 1.f / ssum;
        float o[HD];
#pragma unroll
        for (int dd = 0; dd < HD; ++dd) o[dd] = 0.f;
#pragma unroll
        for (int m = 0; m < DDIM; ++m) {
            float pm = p[m] * inv;
#pragma unroll
            for (int dd = 0; dd < HD; ++dd) o[dd] += pm * qs[m][hc + dd];
        }
#pragma unroll
        for (int q4 = 0; q4 < 4; ++q4) {
            float4 ov = {o[q4*4], o[q4*4+1], o[q4*4+2], o[q4*4+3]};
            *(float4*)&q[((size_t)l * HWW + hw) * CC + hc + q4 * 4] = ov;
        }
    }
}

// ---------------------------------------------------------------------------
// Kernel 3: spatial attention — sequences over hw (L=1024) per d, per head.
// One block per (d, head), 512 threads (8 waves -> 2 waves/SIMD), 2 rows per
// thread. Whole Q-slice (1024 x 16 fp32 = 64 KB) in LDS; per-key reads are
// wave-uniform (LDS broadcast, conflict-free) and amortized over both rows.
// Query rows pre-scaled by SCALE2*log2e so softmax is a bare v_exp_f32
// (scores bounded, no max subtraction needed — mathematically identical).
// In-place on q (each block covers its full (d,h) slice; loads complete
// before any write).
// ---------------------------------------------------------------------------
__global__ __launch_bounds__(512) void attn_spat_kernel(float* __restrict__ q)
{
    __shared__ __align__(16) float qs[HWW][HD];   // 64 KB
    const int d   = blockIdx.x;
    const int h   = blockIdx.y;
    const int tid = threadIdx.x;
    const size_t base = (size_t)d * HWW * CC + h * HD;
    for (int i = tid; i < HWW * 4; i += 512) {
        int row = i >> 2, q4 = i & 3;
        ((float4*)&qs[row][0])[q4] = *(const float4*)&q[base + (size_t)row * CC + q4 * 4];
    }
    __syncthreads();
    const float k2 = SCALE2 * 1.44269504f;   // fold softmax scale + log2(e)
    float qr[2][HD];
#pragma unroll
    for (int r = 0; r < 2; ++r)
#pragma unroll
        for (int dd = 0; dd < HD; ++dd) qr[r][dd] = qs[tid + r * 512][dd] * k2;
    float acc[2][HD];
#pragma unroll
    for (int r = 0; r < 2; ++r)
#pragma unroll
        for (int dd = 0; dd < HD; ++dd) acc[r][dd] = 0.f;
    float ssum[2] = {0.f, 0.f};

#pragma unroll 2
    for (int m = 0; m < HWW; ++m) {
        float4 qa = ((const float4*)&qs[m][0])[0];
        float4 qb = ((const float4*)&qs[m][0])[1];
        float4 qc = ((const float4*)&qs[m][0])[2];
        float4 qd = ((const float4*)&qs[m][0])[3];
        float qm[HD] = {qa.x,qa.y,qa.z,qa.w, qb.x,qb.y,qb.z,qb.w,
                        qc.x,qc.y,qc.z,qc.w, qd.x,qd.y,qd.z,qd.w};
#pragma unroll
        for (int r = 0; r < 2; ++r) {
            float s = 0.f;
#pragma unroll
            for (int dd = 0; dd < HD; ++dd) s += qr[r][dd] * qm[dd];
            float pe = __builtin_amdgcn_exp2f(s);   // exp(score) with folded scale
            ssum[r] += pe;
#pragma unroll
            for (int dd = 0; dd < HD; ++dd) acc[r][dd] += pe * qm[dd];
        }
    }
#pragma unroll
    for (int r = 0; r < 2; ++r) {
        float inv = 1.f / ssum[r];
        int row = tid + r * 512;
#pragma unroll
        for (int q4 = 0; q4 < 4; ++q4) {
            float4 ov = {acc[r][q4*4]*inv, acc[r][q4*4+1]*inv,
                         acc[r][q4*4+2]*inv, acc[r][q4*4+3]*inv};
            *(float4*)&q[base + (size_t)row * CC + q4 * 4] = ov;
        }
    }
}

// ---------------------------------------------------------------------------
// Kernel 4: column sums over tokens (for the gate's global-average pool).
// Grid (31, 8): 248 blocks of 128 rows each — was 31 blocks (31 CUs only).
// ---------------------------------------------------------------------------
__global__ __launch_bounds__(128) void colsum_kernel(
    const float* __restrict__ a, float* __restrict__ sums)
{
    const int tid = threadIdx.x;
    const float* p = a + ((size_t)blockIdx.x * HWW + (size_t)blockIdx.y * 128) * CC;
    float s = 0.f;
#pragma unroll 4
    for (int r = 0; r < 128; ++r) s += p[(size_t)r * CC + tid];
    atomicAdd(&sums[tid], s);
}

// ---------------------------------------------------------------------------
// Kernel 5: gate. mean -> project through Wp (exact, by linearity) -> Wg -> sigmoid.
// ---------------------------------------------------------------------------
__global__ __launch_bounds__(128) void gate_kernel(
    const float* __restrict__ sums,
    const float* __restrict__ Wp1, const float* __restrict__ bp1,
    const float* __restrict__ Wp2, const float* __restrict__ bp2,
    const float* __restrict__ Wg,  const float* __restrict__ bg,
    float* __restrict__ gate)
{
    __shared__ float mean1[CC], mean2[CC], gi[2 * CC];
    const int c = threadIdx.x;
    const float invT = 1.f / (float)TOK;
    mean1[c] = sums[c] * invT;
    mean2[c] = sums[CC + c] * invT;
    __syncthreads();
    float a1 = bp1[c], a2 = bp2[c];
    for (int k = 0; k < CC; ++k) {
        a1 += mean1[k] * Wp1[k * CC + c];
        a2 += mean2[k] * Wp2[k * CC + c];
    }
    gi[c] = a1; gi[CC + c] = a2;
    __syncthreads();
    float g = bg[c];
    for (int j = 0; j < 2 * CC; ++j) g += gi[j] * Wg[j * CC + c];
    gate[c] = 1.f / (1.f + __expf(-g));
}

// ---------------------------------------------------------------------------
// Kernel 6: output projection + gated combine, one branch per launch.
// mode 0: out[c][t]  = g[c]     * (a@Wp + bp)[t][c]
// mode 1: out[c][t] += (1-g[c]) * (a@Wp + bp)[t][c]
// ---------------------------------------------------------------------------
__global__ __launch_bounds__(256) void proj_kernel(
    const float* __restrict__ a, const float* __restrict__ Wp,
    const float* __restrict__ bp, const float* __restrict__ gate,
    const int mode, float* __restrict__ out)
{
    __shared__ __align__(16) float wsm[CC][64];   // 32 KB [k][co-co0]
    __shared__ __align__(16) float as[8][132];    // k-chunk x tokens (+pad)
    const int tid = threadIdx.x;
    const int t0  = blockIdx.x * 128;
    const int co0 = blockIdx.y * 64;
    for (int i = tid; i < CC * 16; i += 256) {
        int k = i >> 4, q4 = i & 15;
        ((float4*)&wsm[k][0])[q4] = *(const float4*)&Wp[k * CC + co0 + q4 * 4];
    }
    const int tg = tid >> 4;
    const int cg = tid & 15;
    float acc[8][4];
#pragma unroll
    for (int i = 0; i < 8; ++i)
#pragma unroll
        for (int j = 0; j < 4; ++j) acc[i][j] = 0.f;

    for (int k0 = 0; k0 < CC; k0 += 8) {
        __syncthreads();
        for (int i = tid; i < 1024; i += 256) {
            int t = i >> 3, k = i & 7;
            as[k][t] = a[(size_t)(t0 + t) * CC + k0 + k];
        }
        __syncthreads();
#pragma unroll
        for (int k = 0; k < 8; ++k) {
            float4 xa = *(const float4*)&as[k][tg * 8];
            float4 xb = *(const float4*)&as[k][tg * 8 + 4];
            float4 w  = *(const float4*)&wsm[k0 + k][cg * 4];
            float xv[8] = {xa.x, xa.y, xa.z, xa.w, xb.x, xb.y, xb.z, xb.w};
            float wv[4] = {w.x, w.y, w.z, w.w};
#pragma unroll
            for (int i = 0; i < 8; ++i)
#pragma unroll
                for (int j = 0; j < 4; ++j) acc[i][j] += xv[i] * wv[j];
        }
    }
#pragma unroll
    for (int j = 0; j < 4; ++j) {
        int co = co0 + cg * 4 + j;
        float g = gate[co];
        if (mode) g = 1.f - g;
        float b = bp[co];
        float v[8];
#pragma unroll
        for (int i = 0; i < 8; ++i) v[i] = g * (acc[i][j] + b);
        if (mode) {
#pragma unroll
            for (int i = 0; i < 8; ++i) v[i] += out[(size_t)co * TOK + t0 + tg * 8 + i];
        }
        float4 o1 = {v[0], v[1], v[2], v[3]};
        float4 o2 = {v[4], v[5], v[6], v[7]};
        *(float4*)&out[(size_t)co * TOK + t0 + tg * 8]     = o1;
        *(float4*)&out[(size_t)co * TOK + t0 + tg * 8 + 4] = o2;
    }
}

extern "C" void kernel_launch(void* const* d_in, const int* in_sizes, int n_in,
                              void* d_out, int out_size, void* d_ws, size_t ws_size,
                              hipStream_t stream)
{
    const float* x   = (const float*)d_in[0];
    const float* Wq1 = (const float*)d_in[1];
    const float* bq1 = (const float*)d_in[2];
    const float* Wp1 = (const float*)d_in[3];
    const float* bp1 = (const float*)d_in[4];
    const float* Wq2 = (const float*)d_in[5];
    const float* bq2 = (const float*)d_in[6];
    const float* Wp2 = (const float*)d_in[7];
    const float* bp2 = (const float*)d_in[8];
    const float* Wg  = (const float*)d_in[9];
    const float* bg  = (const float*)d_in[10];
    float* out = (float*)d_out;

    float* q1   = (float*)d_ws;                 // spec q / attn-out (in-place), 16.25 MB
    float* q2   = q1 + (size_t)TOK * CC;        // spat q / attn-out (in-place), 16.25 MB
    float* sums = q2 + (size_t)TOK * CC;        // 256 floats
    float* gate = sums + 2 * CC;                // 128 floats

    qproj_kernel<<<dim3(248, 2), 256, 0, stream>>>(x, Wq1, bq1, q1);
    qproj_kernel<<<dim3(248, 2), 256, 0, stream>>>(x, Wq2, bq2, q2);
    attn_spec_kernel<<<dim3(1024), 256, 0, stream>>>(q1);
    attn_spat_kernel<<<dim3(DDIM, NH), 512, 0, stream>>>(q2);
    hipMemsetAsync(sums, 0, 2 * CC * sizeof(float), stream);
    colsum_kernel<<<dim3(DDIM, 8), 128, 0, stream>>>(q1, sums);
    colsum_kernel<<<dim3(DDIM, 8), 128, 0, stream>>>(q2, sums + CC);
    gate_kernel<<<1, 128, 0, stream>>>(sums, Wp1, bp1, Wp2, bp2, Wg, bg, gate);
    proj_kernel<<<dim3(248, 2), 256, 0, stream>>>(q1, Wp1, bp1, gate, 0, out);
    proj_kernel<<<dim3(248, 2), 256, 0, stream>>>(q2, Wp2, bp2, gate, 1, out);
}

// Round 3
// 346.887 us; speedup vs baseline: 1.7940x; 1.5424x over previous
//
#include <hip/hip_runtime.h>
#include <cstddef>

#define CC 128
#define NH 8
#define HD 16
#define DDIM 31
#define HWW 1024
#define TOK 31744   // DDIM * HWW
#define SCALE2 0.0625f   // (HD^-0.5)^2 — both operands of QK^T are pre-scaled in the ref

typedef __attribute__((ext_vector_type(4))) short  short4v;
typedef __attribute__((ext_vector_type(4))) float  float4v;
typedef __attribute__((ext_vector_type(2))) unsigned int uint2v;

__device__ inline unsigned bf16rne(float f) {
    unsigned u = __float_as_uint(f);
    return (u + 0x7fffu + ((u >> 16) & 1u)) >> 16;
}

// ---------------------------------------------------------------------------
// Kernel 1: Q projection.  q[t][c] = sum_ci x[ci][t] * Wq[ci][c] + bq[c]
// ---------------------------------------------------------------------------
__global__ __launch_bounds__(256) void qproj_kernel(
    const float* __restrict__ x, const float* __restrict__ Wq,
    const float* __restrict__ bq, float* __restrict__ qout)
{
    __shared__ __align__(16) float wts[CC][64];   // 32 KB  [ci][co-co0]
    __shared__ __align__(16) float xs[8][128];    // 4 KB   [ci-chunk][t]
    const int tid = threadIdx.x;
    const int t0  = blockIdx.x * 128;
    const int co0 = blockIdx.y * 64;

    for (int i = tid; i < CC * 16; i += 256) {
        int k = i >> 4, q4 = i & 15;
        ((float4*)&wts[k][0])[q4] = *(const float4*)&Wq[k * CC + co0 + q4 * 4];
    }
    const int tg = tid >> 4;
    const int cg = tid & 15;
    float acc[8][4];
#pragma unroll
    for (int i = 0; i < 8; ++i)
#pragma unroll
        for (int j = 0; j < 4; ++j) acc[i][j] = 0.f;

    for (int c0 = 0; c0 < CC; c0 += 8) {
        __syncthreads();
        for (int i = tid; i < 1024; i += 256) {
            int r = i >> 7, t = i & 127;
            xs[r][t] = x[(size_t)(c0 + r) * TOK + t0 + t];
        }
        __syncthreads();
#pragma unroll
        for (int r = 0; r < 8; ++r) {
            float4 xa = *(const float4*)&xs[r][tg * 8];
            float4 xb = *(const float4*)&xs[r][tg * 8 + 4];
            float4 w  = *(const float4*)&wts[c0 + r][cg * 4];
            float xv[8] = {xa.x, xa.y, xa.z, xa.w, xb.x, xb.y, xb.z, xb.w};
            float wv[4] = {w.x, w.y, w.z, w.w};
#pragma unroll
            for (int i = 0; i < 8; ++i)
#pragma unroll
                for (int j = 0; j < 4; ++j) acc[i][j] += xv[i] * wv[j];
        }
    }
    float bv[4];
#pragma unroll
    for (int j = 0; j < 4; ++j) bv[j] = bq[co0 + cg * 4 + j];
#pragma unroll
    for (int i = 0; i < 8; ++i) {
        int t = t0 + tg * 8 + i;
        float4 o = {acc[i][0] + bv[0], acc[i][1] + bv[1],
                    acc[i][2] + bv[2], acc[i][3] + bv[3]};
        *(float4*)&qout[(size_t)t * CC + co0 + cg * 4] = o;
    }
}

// ---------------------------------------------------------------------------
// Kernel 2: spectral attention — sequences over d (L=31) per (h,w), 8 heads.
// ---------------------------------------------------------------------------
__global__ __launch_bounds__(256) void attn_spec_kernel(float* __restrict__ q)
{
    __shared__ __align__(16) float qs[DDIM][CC];   // 15.9 KB
    const int hw  = blockIdx.x;
    const int tid = threadIdx.x;
    for (int i = tid; i < DDIM * 32; i += 256) {
        int d = i >> 5, c4 = i & 31;
        ((float4*)&qs[d][0])[c4] = *(const float4*)&q[((size_t)d * HWW + hw) * CC + c4 * 4];
    }
    __syncthreads();
    if (tid < NH * DDIM) {
        const int h = tid / DDIM;
        const int l = tid % DDIM;
        const int hc = h * HD;
        float qr[HD];
#pragma unroll
        for (int dd = 0; dd < HD; ++dd) qr[dd] = qs[l][hc + dd];
        float p[DDIM];
        float smax = -1e30f;
#pragma unroll
        for (int m = 0; m < DDIM; ++m) {
            float s = 0.f;
#pragma unroll
            for (int dd = 0; dd < HD; ++dd) s += qr[dd] * qs[m][hc + dd];
            s *= SCALE2;
            p[m] = s;
            smax = fmaxf(smax, s);
        }
        float ssum = 0.f;
#pragma unroll
        for (int m = 0; m < DDIM; ++m) { p[m] = __expf(p[m] - smax); ssum += p[m]; }
        float inv = 1.f / ssum;
        float o[HD];
#pragma unroll
        for (int dd = 0; dd < HD; ++dd) o[dd] = 0.f;
#pragma unroll
        for (int m = 0; m < DDIM; ++m) {
            float pm = p[m] * inv;
#pragma unroll
            for (int dd = 0; dd < HD; ++dd) o[dd] += pm * qs[m][hc + dd];
        }
#pragma unroll
        for (int q4 = 0; q4 < 4; ++q4) {
            float4 ov = {o[q4*4], o[q4*4+1], o[q4*4+2], o[q4*4+3]};
            *(float4*)&q[((size_t)l * HWW + hw) * CC + hc + q4 * 4] = ov;
        }
    }
}

// ---------------------------------------------------------------------------
// Kernel 3: spatial attention via bf16 MFMA (16x16x16), L=1024, d=16.
// One block per (d, head), 512 threads = 8 waves; wave owns 128 query rows.
// Trick: compute S^T tiles (A=keys, B=queries). exp(S) is symmetric, and
// the 16x16 C-layout (row=quad*4+reg, col=lane&15) IS the A-operand layout
// (A[l=lane&15][k=quad*4+j]) for the P·V MFMA — P stays in registers, no
// transpose/LDS round-trip. Row-normalize at the end (sum of bf16-truncated
// E values, so truncation bias cancels in the softmax quotient).
// In-place on q: full slice staged to LDS before any global write.
// ---------------------------------------------------------------------------
#define QTP 1032   // padded QT row stride (ushort) — breaks 16-way bank conflict
__global__ __launch_bounds__(512) void attn_spat_kernel(float* __restrict__ q)
{
    __shared__ ushort Qs[HWW * HD];    // [row][d] bf16, 32 KB
    __shared__ ushort QTs[HD * QTP];   // [d][row] bf16 padded, 33 KB
    const int tid = threadIdx.x;
    const int d   = blockIdx.x;
    const int h   = blockIdx.y;
    const size_t base = (size_t)d * HWW * CC + h * HD;

    // stage fp32 -> bf16 (RNE), both row-major and transposed copies
    for (int i = tid; i < HWW * 4; i += 512) {
        int row = i >> 2, q4 = i & 3;
        float4 v = *(const float4*)&q[base + (size_t)row * CC + q4 * 4];
        unsigned s0 = bf16rne(v.x), s1 = bf16rne(v.y);
        unsigned s2 = bf16rne(v.z), s3 = bf16rne(v.w);
        *(uint2*)&Qs[row * HD + q4 * 4] = make_uint2(s0 | (s1 << 16), s2 | (s3 << 16));
        QTs[(q4 * 4 + 0) * QTP + row] = (ushort)s0;
        QTs[(q4 * 4 + 1) * QTP + row] = (ushort)s1;
        QTs[(q4 * 4 + 2) * QTP + row] = (ushort)s2;
        QTs[(q4 * 4 + 3) * QTP + row] = (ushort)s3;
    }
    __syncthreads();

    const int lane = tid & 63;
    const int l    = lane & 15;
    const int quad = lane >> 4;
    const int Rw   = (tid >> 6) * 128;   // wave's query-row block

    // preload query B-frags (also valid as key A-frags: same layout/data)
    short4v qf[8];
#pragma unroll
    for (int lt = 0; lt < 8; ++lt)
        qf[lt] = *(short4v*)&Qs[(Rw + lt * 16 + l) * HD + quad * 4];

    float4v acc[8];
    float persum[8];
#pragma unroll
    for (int lt = 0; lt < 8; ++lt) {
        acc[lt] = (float4v){0.f, 0.f, 0.f, 0.f};
        persum[lt] = 0.f;
    }
    const float k2 = SCALE2 * 1.44269504f;   // fold softmax scale + log2(e)

#pragma unroll 2
    for (int mt = 0; mt < 64; ++mt) {
        const int m0 = mt * 16;
        short4v ka = *(short4v*)&Qs[(m0 + l) * HD + quad * 4];          // keys A-frag
        short4v vb = *(short4v*)&QTs[l * QTP + m0 + quad * 4];          // V B-frag
#pragma unroll
        for (int lt = 0; lt < 8; ++lt) {
            // S^T tile: lane holds S[l0+lane&15][m0+quad*4+reg], reg 0..3
            float4v s = __builtin_amdgcn_mfma_f32_16x16x16bf16_1k(
                ka, qf[lt], (float4v){0.f, 0.f, 0.f, 0.f}, 0, 0, 0);
            unsigned u0 = __float_as_uint(__builtin_amdgcn_exp2f(s[0] * k2)) & 0xffff0000u;
            unsigned u1 = __float_as_uint(__builtin_amdgcn_exp2f(s[1] * k2)) & 0xffff0000u;
            unsigned u2 = __float_as_uint(__builtin_amdgcn_exp2f(s[2] * k2)) & 0xffff0000u;
            unsigned u3 = __float_as_uint(__builtin_amdgcn_exp2f(s[3] * k2)) & 0xffff0000u;
            persum[lt] += (__uint_as_float(u0) + __uint_as_float(u1)) +
                          (__uint_as_float(u2) + __uint_as_float(u3));
            uint2v pu = {(u0 >> 16) | u1, (u2 >> 16) | u3};
            short4v pf = __builtin_bit_cast(short4v, pu);   // P in A-layout
            acc[lt] = __builtin_amdgcn_mfma_f32_16x16x16bf16_1k(pf, vb, acc[lt], 0, 0, 0);
        }
    }

    // normalize and store (in-place; all reads were from LDS)
#pragma unroll
    for (int lt = 0; lt < 8; ++lt) {
        float a = persum[lt];
        a += __shfl_xor(a, 16);
        a += __shfl_xor(a, 32);          // all lanes: rowsum for row l=lane&15
        float inv = 1.f / a;
#pragma unroll
        for (int reg = 0; reg < 4; ++reg) {
            float iv = __shfl(inv, quad * 4 + reg);   // rowsum for row quad*4+reg
            int row = Rw + lt * 16 + quad * 4 + reg;
            q[base + (size_t)row * CC + l] = acc[lt][reg] * iv;
        }
    }
}

// ---------------------------------------------------------------------------
// Kernel 4: column sums over tokens (for the gate's global-average pool).
// ---------------------------------------------------------------------------
__global__ __launch_bounds__(128) void colsum_kernel(
    const float* __restrict__ a, float* __restrict__ sums)
{
    const int tid = threadIdx.x;
    const float* p = a + ((size_t)blockIdx.x * HWW + (size_t)blockIdx.y * 128) * CC;
    float s = 0.f;
#pragma unroll 4
    for (int r = 0; r < 128; ++r) s += p[(size_t)r * CC + tid];
    atomicAdd(&sums[tid], s);
}

// ---------------------------------------------------------------------------
// Kernel 5: gate. mean -> project through Wp (exact, by linearity) -> Wg -> sigmoid.
// ---------------------------------------------------------------------------
__global__ __launch_bounds__(128) void gate_kernel(
    const float* __restrict__ sums,
    const float* __restrict__ Wp1, const float* __restrict__ bp1,
    const float* __restrict__ Wp2, const float* __restrict__ bp2,
    const float* __restrict__ Wg,  const float* __restrict__ bg,
    float* __restrict__ gate)
{
    __shared__ float mean1[CC], mean2[CC], gi[2 * CC];
    const int c = threadIdx.x;
    const float invT = 1.f / (float)TOK;
    mean1[c] = sums[c] * invT;
    mean2[c] = sums[CC + c] * invT;
    __syncthreads();
    float a1 = bp1[c], a2 = bp2[c];
    for (int k = 0; k < CC; ++k) {
        a1 += mean1[k] * Wp1[k * CC + c];
        a2 += mean2[k] * Wp2[k * CC + c];
    }
    gi[c] = a1; gi[CC + c] = a2;
    __syncthreads();
    float g = bg[c];
    for (int j = 0; j < 2 * CC; ++j) g += gi[j] * Wg[j * CC + c];
    gate[c] = 1.f / (1.f + __expf(-g));
}

// ---------------------------------------------------------------------------
// Kernel 6: output projection + gated combine, one branch per launch.
// ---------------------------------------------------------------------------
__global__ __launch_bounds__(256) void proj_kernel(
    const float* __restrict__ a, const float* __restrict__ Wp,
    const float* __restrict__ bp, const float* __restrict__ gate,
    const int mode, float* __restrict__ out)
{
    __shared__ __align__(16) float wsm[CC][64];   // 32 KB [k][co-co0]
    __shared__ __align__(16) float as[8][132];    // k-chunk x tokens (+pad)
    const int tid = threadIdx.x;
    const int t0  = blockIdx.x * 128;
    const int co0 = blockIdx.y * 64;
    for (int i = tid; i < CC * 16; i += 256) {
        int k = i >> 4, q4 = i & 15;
        ((float4*)&wsm[k][0])[q4] = *(const float4*)&Wp[k * CC + co0 + q4 * 4];
    }
    const int tg = tid >> 4;
    const int cg = tid & 15;
    float acc[8][4];
#pragma unroll
    for (int i = 0; i < 8; ++i)
#pragma unroll
        for (int j = 0; j < 4; ++j) acc[i][j] = 0.f;

    for (int k0 = 0; k0 < CC; k0 += 8) {
        __syncthreads();
        for (int i = tid; i < 1024; i += 256) {
            int t = i >> 3, k = i & 7;
            as[k][t] = a[(size_t)(t0 + t) * CC + k0 + k];
        }
        __syncthreads();
#pragma unroll
        for (int k = 0; k < 8; ++k) {
            float4 xa = *(const float4*)&as[k][tg * 8];
            float4 xb = *(const float4*)&as[k][tg * 8 + 4];
            float4 w  = *(const float4*)&wsm[k0 + k][cg * 4];
            float xv[8] = {xa.x, xa.y, xa.z, xa.w, xb.x, xb.y, xb.z, xb.w};
            float wv[4] = {w.x, w.y, w.z, w.w};
#pragma unroll
            for (int i = 0; i < 8; ++i)
#pragma unroll
                for (int j = 0; j < 4; ++j) acc[i][j] += xv[i] * wv[j];
        }
    }
#pragma unroll
    for (int j = 0; j < 4; ++j) {
        int co = co0 + cg * 4 + j;
        float g = gate[co];
        if (mode) g = 1.f - g;
        float b = bp[co];
        float v[8];
#pragma unroll
        for (int i = 0; i < 8; ++i) v[i] = g * (acc[i][j] + b);
        if (mode) {
#pragma unroll
            for (int i = 0; i < 8; ++i) v[i] += out[(size_t)co * TOK + t0 + tg * 8 + i];
        }
        float4 o1 = {v[0], v[1], v[2], v[3]};
        float4 o2 = {v[4], v[5], v[6], v[7]};
        *(float4*)&out[(size_t)co * TOK + t0 + tg * 8]     = o1;
        *(float4*)&out[(size_t)co * TOK + t0 + tg * 8 + 4] = o2;
    }
}

extern "C" void kernel_launch(void* const* d_in, const int* in_sizes, int n_in,
                              void* d_out, int out_size, void* d_ws, size_t ws_size,
                              hipStream_t stream)
{
    const float* x   = (const float*)d_in[0];
    const float* Wq1 = (const float*)d_in[1];
    const float* bq1 = (const float*)d_in[2];
    const float* Wp1 = (const float*)d_in[3];
    const float* bp1 = (const float*)d_in[4];
    const float* Wq2 = (const float*)d_in[5];
    const float* bq2 = (const float*)d_in[6];
    const float* Wp2 = (const float*)d_in[7];
    const float* bp2 = (const float*)d_in[8];
    const float* Wg  = (const float*)d_in[9];
    const float* bg  = (const float*)d_in[10];
    float* out = (float*)d_out;

    float* q1   = (float*)d_ws;                 // spec q / attn-out (in-place)
    float* q2   = q1 + (size_t)TOK * CC;        // spat q / attn-out (in-place)
    float* sums = q2 + (size_t)TOK * CC;        // 256 floats
    float* gate = sums + 2 * CC;                // 128 floats

    qproj_kernel<<<dim3(248, 2), 256, 0, stream>>>(x, Wq1, bq1, q1);
    qproj_kernel<<<dim3(248, 2), 256, 0, stream>>>(x, Wq2, bq2, q2);
    attn_spec_kernel<<<dim3(1024), 256, 0, stream>>>(q1);
    attn_spat_kernel<<<dim3(DDIM, NH), 512, 0, stream>>>(q2);
    hipMemsetAsync(sums, 0, 2 * CC * sizeof(float), stream);
    colsum_kernel<<<dim3(DDIM, 8), 128, 0, stream>>>(q1, sums);
    colsum_kernel<<<dim3(DDIM, 8), 128, 0, stream>>>(q2, sums + CC);
    gate_kernel<<<1, 128, 0, stream>>>(sums, Wp1, bp1, Wp2, bp2, Wg, bg, gate);
    proj_kernel<<<dim3(248, 2), 256, 0, stream>>>(q1, Wp1, bp1, gate, 0, out);
    proj_kernel<<<dim3(248, 2), 256, 0, stream>>>(q2, Wp2, bp2, gate, 1, out);
}

// Round 4
// 302.101 us; speedup vs baseline: 2.0599x; 1.1482x over previous
//
#include <hip/hip_runtime.h>
#include <cstddef>

#define CC 128
#define NH 8
#define HD 16
#define DDIM 31
#define HWW 1024
#define TOK 31744   // DDIM * HWW
#define SCALE2 0.0625f   // (HD^-0.5)^2 — both QK^T operands pre-scaled in the ref

typedef __attribute__((ext_vector_type(4))) short  short4v;
typedef __attribute__((ext_vector_type(4))) float  float4v;

__device__ inline unsigned bf16rne(float f) {
    unsigned u = __float_as_uint(f);
    return (u + 0x7fffu + ((u >> 16) & 1u)) >> 16;
}
__device__ inline float bf2f(unsigned h) { return __uint_as_float(h << 16); }

// ---------------------------------------------------------------------------
// Kernel 1: projection GEMM via bf16x2-split MFMA (near-fp32 accuracy).
// D[co][t] = sum_k W[k][co] * act_val(k, t)   (A-operand = W^T, proven layouts)
// MODE 0 (qproj): act = x in [k=ci][t] layout; store q[t][co] (+bias)
// MODE 1 (proj):  act = attn_out in [t][k] layout; store out[co][t] with
//                 bias + sigmoid-gate fuse (gmode 0: g*( ), 1: += (1-g)*( )).
// 3-term split: Whi*Bhi + Whi*Blo + Wlo*Bhi  (drop lo*lo, ~1e-6 rel).
// Block 512 thr = 8 waves; tile 128co x 128t; K=128 staged whole in LDS.
// ---------------------------------------------------------------------------
#define WTS 140   // W^T LDS row stride (ushorts): 70 dw ≡ 6 mod 32 — b64 reads conflict-free
template<int MODE>
__global__ __launch_bounds__(512) void mfma_proj_kernel(
    const float* __restrict__ act, const float* __restrict__ W,
    const float* __restrict__ bias, const float* __restrict__ gatep,
    const int gmode, float* __restrict__ outp)
{
    constexpr int AS = MODE ? 140 : 132;   // act stride: both give conflict-free frag reads
    __shared__ ushort WThi[CC * WTS], WTlo[CC * WTS];  // 71.7 KB
    __shared__ ushort Ahi[CC * AS],  Alo[CC * AS];     // 67.6/71.7 KB
    const int tid = threadIdx.x;
    const int t0  = blockIdx.x * 128;

    // stage W transposed + split (coalesced float4 global reads)
    for (int i = tid; i < CC * CC / 4; i += 512) {
        int co4 = i & 31, k = i >> 5;
        float4 w = *(const float4*)&W[k * CC + co4 * 4];
        float wv[4] = {w.x, w.y, w.z, w.w};
#pragma unroll
        for (int e = 0; e < 4; ++e) {
            unsigned hi = bf16rne(wv[e]);
            unsigned lo = bf16rne(wv[e] - bf2f(hi));
            WThi[(co4 * 4 + e) * WTS + k] = (ushort)hi;
            WTlo[(co4 * 4 + e) * WTS + k] = (ushort)lo;
        }
    }
    // stage activation tile + split
    if (MODE == 0) {
        for (int i = tid; i < CC * 128 / 4; i += 512) {
            int t4 = i & 31, ci = i >> 5;
            float4 v = *(const float4*)&act[(size_t)ci * TOK + t0 + t4 * 4];
            float xv[4] = {v.x, v.y, v.z, v.w};
            unsigned hi[4], lo[4];
#pragma unroll
            for (int e = 0; e < 4; ++e) {
                hi[e] = bf16rne(xv[e]);
                lo[e] = bf16rne(xv[e] - bf2f(hi[e]));
            }
            *(uint2*)&Ahi[ci * AS + t4 * 4] = make_uint2(hi[0] | (hi[1] << 16), hi[2] | (hi[3] << 16));
            *(uint2*)&Alo[ci * AS + t4 * 4] = make_uint2(lo[0] | (lo[1] << 16), lo[2] | (lo[3] << 16));
        }
    } else {
        for (int i = tid; i < 128 * CC / 4; i += 512) {
            int k4 = i & 31, t = i >> 5;
            float4 v = *(const float4*)&act[(size_t)(t0 + t) * CC + k4 * 4];
            float xv[4] = {v.x, v.y, v.z, v.w};
            unsigned hi[4], lo[4];
#pragma unroll
            for (int e = 0; e < 4; ++e) {
                hi[e] = bf16rne(xv[e]);
                lo[e] = bf16rne(xv[e] - bf2f(hi[e]));
            }
            *(uint2*)&Ahi[t * AS + k4 * 4] = make_uint2(hi[0] | (hi[1] << 16), hi[2] | (hi[3] << 16));
            *(uint2*)&Alo[t * AS + k4 * 4] = make_uint2(lo[0] | (lo[1] << 16), lo[2] | (lo[3] << 16));
        }
    }
    __syncthreads();

    const int lane = tid & 63;
    const int l    = lane & 15;
    const int quad = lane >> 4;
    const int co0  = (tid >> 6) * 16;   // wave owns 16 output channels

    float4v acc[8];
#pragma unroll
    for (int nt = 0; nt < 8; ++nt) acc[nt] = (float4v){0.f, 0.f, 0.f, 0.f};

    for (int k0 = 0; k0 < CC; k0 += 16) {
        short4v ah = *(short4v*)&WThi[(co0 + l) * WTS + k0 + quad * 4];
        short4v al = *(short4v*)&WTlo[(co0 + l) * WTS + k0 + quad * 4];
#pragma unroll
        for (int nt = 0; nt < 8; ++nt) {
            short4v bh, bl;
            if (MODE == 0) {
                const int tcol = nt * 16 + l;
#pragma unroll
                for (int j = 0; j < 4; ++j) {
                    bh[j] = (short)Ahi[(k0 + quad * 4 + j) * AS + tcol];
                    bl[j] = (short)Alo[(k0 + quad * 4 + j) * AS + tcol];
                }
            } else {
                bh = *(short4v*)&Ahi[(nt * 16 + l) * AS + k0 + quad * 4];
                bl = *(short4v*)&Alo[(nt * 16 + l) * AS + k0 + quad * 4];
            }
            acc[nt] = __builtin_amdgcn_mfma_f32_16x16x16bf16_1k(ah, bh, acc[nt], 0, 0, 0);
            acc[nt] = __builtin_amdgcn_mfma_f32_16x16x16bf16_1k(ah, bl, acc[nt], 0, 0, 0);
            acc[nt] = __builtin_amdgcn_mfma_f32_16x16x16bf16_1k(al, bh, acc[nt], 0, 0, 0);
        }
    }

    float4 bv = *(const float4*)&bias[co0 + quad * 4];
    float bb[4] = {bv.x, bv.y, bv.z, bv.w};
    if (MODE == 0) {
#pragma unroll
        for (int nt = 0; nt < 8; ++nt) {
            int t = t0 + nt * 16 + l;
            float4 o = {acc[nt][0] + bb[0], acc[nt][1] + bb[1],
                        acc[nt][2] + bb[2], acc[nt][3] + bb[3]};
            *(float4*)&outp[(size_t)t * CC + co0 + quad * 4] = o;
        }
    } else {
        float4 gv = *(const float4*)&gatep[co0 + quad * 4];
        float gg[4] = {gv.x, gv.y, gv.z, gv.w};
        if (gmode) {
#pragma unroll
            for (int e = 0; e < 4; ++e) gg[e] = 1.f - gg[e];
        }
#pragma unroll
        for (int nt = 0; nt < 8; ++nt) {
            int t = t0 + nt * 16 + l;
#pragma unroll
            for (int reg = 0; reg < 4; ++reg) {
                size_t idx = (size_t)(co0 + quad * 4 + reg) * TOK + t;
                float v = gg[reg] * (acc[nt][reg] + bb[reg]);
                if (gmode) v += outp[idx];
                outp[idx] = v;
            }
        }
    }
}

// ---------------------------------------------------------------------------
// Kernel 2: spectral attention — sequences over d (L=31) per (h,w), 8 heads.
// ---------------------------------------------------------------------------
__global__ __launch_bounds__(256) void attn_spec_kernel(float* __restrict__ q)
{
    __shared__ __align__(16) float qs[DDIM][CC];   // 15.9 KB
    const int hw  = blockIdx.x;
    const int tid = threadIdx.x;
    for (int i = tid; i < DDIM * 32; i += 256) {
        int d = i >> 5, c4 = i & 31;
        ((float4*)&qs[d][0])[c4] = *(const float4*)&q[((size_t)d * HWW + hw) * CC + c4 * 4];
    }
    __syncthreads();
    if (tid < NH * DDIM) {
        const int h = tid / DDIM;
        const int l = tid % DDIM;
        const int hc = h * HD;
        float qr[HD];
#pragma unroll
        for (int dd = 0; dd < HD; ++dd) qr[dd] = qs[l][hc + dd];
        float p[DDIM];
        float smax = -1e30f;
#pragma unroll
        for (int m = 0; m < DDIM; ++m) {
            float s = 0.f;
#pragma unroll
            for (int dd = 0; dd < HD; ++dd) s += qr[dd] * qs[m][hc + dd];
            s *= SCALE2;
            p[m] = s;
            smax = fmaxf(smax, s);
        }
        float ssum = 0.f;
#pragma unroll
        for (int m = 0; m < DDIM; ++m) { p[m] = __expf(p[m] - smax); ssum += p[m]; }
        float inv = 1.f / ssum;
        float o[HD];
#pragma unroll
        for (int dd = 0; dd < HD; ++dd) o[dd] = 0.f;
#pragma unroll
        for (int m = 0; m < DDIM; ++m) {
            float pm = p[m] * inv;
#pragma unroll
            for (int dd = 0; dd < HD; ++dd) o[dd] += pm * qs[m][hc + dd];
        }
#pragma unroll
        for (int q4 = 0; q4 < 4; ++q4) {
            float4 ov = {o[q4*4], o[q4*4+1], o[q4*4+2], o[q4*4+3]};
            *(float4*)&q[((size_t)l * HWW + hw) * CC + hc + q4 * 4] = ov;
        }
    }
}

// ---------------------------------------------------------------------------
// Kernel 3: spatial attention via bf16 MFMA (16x16x16), L=1024, d=16.
// S^T trick (A=keys, B=queries): C-layout == A-layout for the P·V MFMA.
// Queries pre-scaled by SCALE2*log2e at frag preload (no per-tile mul).
// Qs stride 20 ushorts (10 dw ≡ 10 mod 32: 16 distinct banks — b64 reads
// conflict-free); QTs stride 1044 (522 dw ≡ 10 — staging writes and vb
// reads conflict-free). In-place on q.
// ---------------------------------------------------------------------------
#define QSS 20
#define QTP 1044
__global__ __launch_bounds__(512) void attn_spat_kernel(float* __restrict__ q)
{
    __shared__ ushort Qs[HWW * QSS];   // [row][d] bf16, 40 KB
    __shared__ ushort QTs[HD * QTP];   // [d][row] bf16, 33.4 KB
    const int tid = threadIdx.x;
    const int d   = blockIdx.x;
    const int h   = blockIdx.y;
    const size_t base = (size_t)d * HWW * CC + h * HD;

    for (int i = tid; i < HWW * 4; i += 512) {
        int row = i >> 2, q4 = i & 3;
        float4 v = *(const float4*)&q[base + (size_t)row * CC + q4 * 4];
        unsigned s0 = bf16rne(v.x), s1 = bf16rne(v.y);
        unsigned s2 = bf16rne(v.z), s3 = bf16rne(v.w);
        *(uint2*)&Qs[row * QSS + q4 * 4] = make_uint2(s0 | (s1 << 16), s2 | (s3 << 16));
        QTs[(q4 * 4 + 0) * QTP + row] = (ushort)s0;
        QTs[(q4 * 4 + 1) * QTP + row] = (ushort)s1;
        QTs[(q4 * 4 + 2) * QTP + row] = (ushort)s2;
        QTs[(q4 * 4 + 3) * QTP + row] = (ushort)s3;
    }
    __syncthreads();

    const int lane = tid & 63;
    const int l    = lane & 15;
    const int quad = lane >> 4;
    const int Rw   = (tid >> 6) * 128;   // wave's query-row block
    const float k2 = SCALE2 * 1.44269504f;

    // preload query B-frags, pre-scaled by k2 (folds softmax scale + log2e)
    short4v qf[8];
#pragma unroll
    for (int lt = 0; lt < 8; ++lt) {
        short4v raw = *(short4v*)&Qs[(Rw + lt * 16 + l) * QSS + quad * 4];
        short4v sc;
#pragma unroll
        for (int e = 0; e < 4; ++e) {
            float f = bf2f((unsigned)(ushort)raw[e]) * k2;
            sc[e] = (short)bf16rne(f);
        }
        qf[lt] = sc;
    }

    float4v acc[8];
    float persum[8];
#pragma unroll
    for (int lt = 0; lt < 8; ++lt) {
        acc[lt] = (float4v){0.f, 0.f, 0.f, 0.f};
        persum[lt] = 0.f;
    }

#pragma unroll 2
    for (int mt = 0; mt < 64; ++mt) {
        const int m0 = mt * 16;
        short4v ka = *(short4v*)&Qs[(m0 + l) * QSS + quad * 4];       // keys A-frag
        short4v vb = *(short4v*)&QTs[l * QTP + m0 + quad * 4];        // V B-frag
#pragma unroll
        for (int lt = 0; lt < 8; ++lt) {
            float4v s = __builtin_amdgcn_mfma_f32_16x16x16bf16_1k(
                ka, qf[lt], (float4v){0.f, 0.f, 0.f, 0.f}, 0, 0, 0);
            unsigned u0 = __float_as_uint(__builtin_amdgcn_exp2f(s[0])) & 0xffff0000u;
            unsigned u1 = __float_as_uint(__builtin_amdgcn_exp2f(s[1])) & 0xffff0000u;
            unsigned u2 = __float_as_uint(__builtin_amdgcn_exp2f(s[2])) & 0xffff0000u;
            unsigned u3 = __float_as_uint(__builtin_amdgcn_exp2f(s[3])) & 0xffff0000u;
            persum[lt] += (__uint_as_float(u0) + __uint_as_float(u1)) +
                          (__uint_as_float(u2) + __uint_as_float(u3));
            short4v pf;
            pf[0] = (short)(u0 >> 16); pf[1] = (short)(u1 >> 16);
            pf[2] = (short)(u2 >> 16); pf[3] = (short)(u3 >> 16);
            acc[lt] = __builtin_amdgcn_mfma_f32_16x16x16bf16_1k(pf, vb, acc[lt], 0, 0, 0);
        }
    }

#pragma unroll
    for (int lt = 0; lt < 8; ++lt) {
        float a = persum[lt];
        a += __shfl_xor(a, 16);
        a += __shfl_xor(a, 32);
        float inv = 1.f / a;
#pragma unroll
        for (int reg = 0; reg < 4; ++reg) {
            float iv = __shfl(inv, quad * 4 + reg);
            int row = Rw + lt * 16 + quad * 4 + reg;
            q[base + (size_t)row * CC + l] = acc[lt][reg] * iv;
        }
    }
}

// ---------------------------------------------------------------------------
// Kernel 4: column sums over tokens (for the gate's global-average pool).
// ---------------------------------------------------------------------------
__global__ __launch_bounds__(128) void colsum_kernel(
    const float* __restrict__ a, float* __restrict__ sums)
{
    const int tid = threadIdx.x;
    const float* p = a + ((size_t)blockIdx.x * HWW + (size_t)blockIdx.y * 128) * CC;
    float s = 0.f;
#pragma unroll 4
    for (int r = 0; r < 128; ++r) s += p[(size_t)r * CC + tid];
    atomicAdd(&sums[tid], s);
}

// ---------------------------------------------------------------------------
// Kernel 5: gate. mean -> project through Wp (exact, by linearity) -> Wg -> sigmoid.
// ---------------------------------------------------------------------------
__global__ __launch_bounds__(128) void gate_kernel(
    const float* __restrict__ sums,
    const float* __restrict__ Wp1, const float* __restrict__ bp1,
    const float* __restrict__ Wp2, const float* __restrict__ bp2,
    const float* __restrict__ Wg,  const float* __restrict__ bg,
    float* __restrict__ gate)
{
    __shared__ float mean1[CC], mean2[CC], gi[2 * CC];
    const int c = threadIdx.x;
    const float invT = 1.f / (float)TOK;
    mean1[c] = sums[c] * invT;
    mean2[c] = sums[CC + c] * invT;
    __syncthreads();
    float a1 = bp1[c], a2 = bp2[c];
    for (int k = 0; k < CC; ++k) {
        a1 += mean1[k] * Wp1[k * CC + c];
        a2 += mean2[k] * Wp2[k * CC + c];
    }
    gi[c] = a1; gi[CC + c] = a2;
    __syncthreads();
    float g = bg[c];
    for (int j = 0; j < 2 * CC; ++j) g += gi[j] * Wg[j * CC + c];
    gate[c] = 1.f / (1.f + __expf(-g));
}

extern "C" void kernel_launch(void* const* d_in, const int* in_sizes, int n_in,
                              void* d_out, int out_size, void* d_ws, size_t ws_size,
                              hipStream_t stream)
{
    const float* x   = (const float*)d_in[0];
    const float* Wq1 = (const float*)d_in[1];
    const float* bq1 = (const float*)d_in[2];
    const float* Wp1 = (const float*)d_in[3];
    const float* bp1 = (const float*)d_in[4];
    const float* Wq2 = (const float*)d_in[5];
    const float* bq2 = (const float*)d_in[6];
    const float* Wp2 = (const float*)d_in[7];
    const float* bp2 = (const float*)d_in[8];
    const float* Wg  = (const float*)d_in[9];
    const float* bg  = (const float*)d_in[10];
    float* out = (float*)d_out;

    float* q1   = (float*)d_ws;                 // spec q / attn-out (in-place)
    float* q2   = q1 + (size_t)TOK * CC;        // spat q / attn-out (in-place)
    float* sums = q2 + (size_t)TOK * CC;        // 256 floats
    float* gate = sums + 2 * CC;                // 128 floats

    mfma_proj_kernel<0><<<dim3(248), 512, 0, stream>>>(x, Wq1, bq1, nullptr, 0, q1);
    mfma_proj_kernel<0><<<dim3(248), 512, 0, stream>>>(x, Wq2, bq2, nullptr, 0, q2);
    attn_spec_kernel<<<dim3(1024), 256, 0, stream>>>(q1);
    attn_spat_kernel<<<dim3(DDIM, NH), 512, 0, stream>>>(q2);
    hipMemsetAsync(sums, 0, 2 * CC * sizeof(float), stream);
    colsum_kernel<<<dim3(DDIM, 8), 128, 0, stream>>>(q1, sums);
    colsum_kernel<<<dim3(DDIM, 8), 128, 0, stream>>>(q2, sums + CC);
    gate_kernel<<<1, 128, 0, stream>>>(sums, Wp1, bp1, Wp2, bp2, Wg, bg, gate);
    mfma_proj_kernel<1><<<dim3(248), 512, 0, stream>>>(q1, Wp1, bp1, gate, 0, out);
    mfma_proj_kernel<1><<<dim3(248), 512, 0, stream>>>(q2, Wp2, bp2, gate, 1, out);
}

// Round 5
// 242.791 us; speedup vs baseline: 2.5631x; 1.2443x over previous
//
#include <hip/hip_runtime.h>
#include <cstddef>

#define CC 128
#define NH 8
#define HD 16
#define DDIM 31
#define HWW 1024
#define TOK 31744   // DDIM * HWW
#define SCALE2 0.0625f   // (HD^-0.5)^2 — both QK^T operands pre-scaled in the ref

typedef __attribute__((ext_vector_type(4))) short  short4v;
typedef __attribute__((ext_vector_type(4))) float  float4v;

__device__ inline unsigned bf16rne(float f) {
    unsigned u = __float_as_uint(f);
    return (u + 0x7fffu + ((u >> 16) & 1u)) >> 16;
}
__device__ inline float bf2f(unsigned h) { return __uint_as_float(h << 16); }

// ---------------------------------------------------------------------------
// Kernel 1: projection GEMM via bf16x2-split MFMA (near-fp32 accuracy).
// D[co][t] = sum_k W[k][co] * act_val(k, t)   (A-operand = W^T)
// MODE 0 (qproj): act = x in [k=ci][t] layout — staged TRANSPOSED into LDS
//                 (scalar writes once, vector b64 frag reads in the K-loop).
// MODE 1 (proj):  act = attn_out in [t][k] layout — direct vector staging.
// Inner loop is identical for both modes. 3-term split: hi*hi + hi*lo + lo*hi.
// ---------------------------------------------------------------------------
#define WTS 140   // LDS row stride (ushorts): 70 dw ≡ 6 mod 32 — b64 reads conflict-free
template<int MODE>
__global__ __launch_bounds__(512) void mfma_proj_kernel(
    const float* __restrict__ act, const float* __restrict__ W,
    const float* __restrict__ bias, const float* __restrict__ gatep,
    const int gmode, float* __restrict__ outp)
{
    __shared__ ushort WThi[CC * WTS], WTlo[CC * WTS];  // 71.7 KB
    __shared__ ushort Ahi[CC * WTS],  Alo[CC * WTS];   // 71.7 KB  [t][k] both modes
    const int tid = threadIdx.x;
    const int t0  = blockIdx.x * 128;

    // stage W transposed + split (coalesced float4 global reads)
    for (int i = tid; i < CC * CC / 4; i += 512) {
        int co4 = i & 31, k = i >> 5;
        float4 w = *(const float4*)&W[k * CC + co4 * 4];
        float wv[4] = {w.x, w.y, w.z, w.w};
#pragma unroll
        for (int e = 0; e < 4; ++e) {
            unsigned hi = bf16rne(wv[e]);
            unsigned lo = bf16rne(wv[e] - bf2f(hi));
            WThi[(co4 * 4 + e) * WTS + k] = (ushort)hi;
            WTlo[(co4 * 4 + e) * WTS + k] = (ushort)lo;
        }
    }
    // stage activation tile + split, into [t][k] layout
    if (MODE == 0) {
        for (int i = tid; i < CC * 128 / 4; i += 512) {
            int t4 = i & 31, ci = i >> 5;
            float4 v = *(const float4*)&act[(size_t)ci * TOK + t0 + t4 * 4];
            float xv[4] = {v.x, v.y, v.z, v.w};
#pragma unroll
            for (int e = 0; e < 4; ++e) {
                unsigned hi = bf16rne(xv[e]);
                unsigned lo = bf16rne(xv[e] - bf2f(hi));
                Ahi[(t4 * 4 + e) * WTS + ci] = (ushort)hi;   // transpose at write
                Alo[(t4 * 4 + e) * WTS + ci] = (ushort)lo;
            }
        }
    } else {
        for (int i = tid; i < 128 * CC / 4; i += 512) {
            int k4 = i & 31, t = i >> 5;
            float4 v = *(const float4*)&act[(size_t)(t0 + t) * CC + k4 * 4];
            float xv[4] = {v.x, v.y, v.z, v.w};
            unsigned hi[4], lo[4];
#pragma unroll
            for (int e = 0; e < 4; ++e) {
                hi[e] = bf16rne(xv[e]);
                lo[e] = bf16rne(xv[e] - bf2f(hi[e]));
            }
            *(uint2*)&Ahi[t * WTS + k4 * 4] = make_uint2(hi[0] | (hi[1] << 16), hi[2] | (hi[3] << 16));
            *(uint2*)&Alo[t * WTS + k4 * 4] = make_uint2(lo[0] | (lo[1] << 16), lo[2] | (lo[3] << 16));
        }
    }
    __syncthreads();

    const int lane = tid & 63;
    const int l    = lane & 15;
    const int quad = lane >> 4;
    const int co0  = (tid >> 6) * 16;   // wave owns 16 output channels

    float4v acc[8];
#pragma unroll
    for (int nt = 0; nt < 8; ++nt) acc[nt] = (float4v){0.f, 0.f, 0.f, 0.f};

    for (int k0 = 0; k0 < CC; k0 += 16) {
        short4v ah = *(short4v*)&WThi[(co0 + l) * WTS + k0 + quad * 4];
        short4v al = *(short4v*)&WTlo[(co0 + l) * WTS + k0 + quad * 4];
#pragma unroll
        for (int nt = 0; nt < 8; ++nt) {
            short4v bh = *(short4v*)&Ahi[(nt * 16 + l) * WTS + k0 + quad * 4];
            short4v bl = *(short4v*)&Alo[(nt * 16 + l) * WTS + k0 + quad * 4];
            acc[nt] = __builtin_amdgcn_mfma_f32_16x16x16bf16_1k(ah, bh, acc[nt], 0, 0, 0);
            acc[nt] = __builtin_amdgcn_mfma_f32_16x16x16bf16_1k(ah, bl, acc[nt], 0, 0, 0);
            acc[nt] = __builtin_amdgcn_mfma_f32_16x16x16bf16_1k(al, bh, acc[nt], 0, 0, 0);
        }
    }

    float4 bv = *(const float4*)&bias[co0 + quad * 4];
    float bb[4] = {bv.x, bv.y, bv.z, bv.w};
    if (MODE == 0) {
#pragma unroll
        for (int nt = 0; nt < 8; ++nt) {
            int t = t0 + nt * 16 + l;
            float4 o = {acc[nt][0] + bb[0], acc[nt][1] + bb[1],
                        acc[nt][2] + bb[2], acc[nt][3] + bb[3]};
            *(float4*)&outp[(size_t)t * CC + co0 + quad * 4] = o;
        }
    } else {
        float4 gv = *(const float4*)&gatep[co0 + quad * 4];
        float gg[4] = {gv.x, gv.y, gv.z, gv.w};
        if (gmode) {
#pragma unroll
            for (int e = 0; e < 4; ++e) gg[e] = 1.f - gg[e];
        }
#pragma unroll
        for (int nt = 0; nt < 8; ++nt) {
            int t = t0 + nt * 16 + l;
#pragma unroll
            for (int reg = 0; reg < 4; ++reg) {
                size_t idx = (size_t)(co0 + quad * 4 + reg) * TOK + t;
                float v = gg[reg] * (acc[nt][reg] + bb[reg]);
                if (gmode) v += outp[idx];
                outp[idx] = v;
            }
        }
    }
}

// ---------------------------------------------------------------------------
// Kernel 2: spectral attention via bf16 MFMA. L=31 (pad→32), d=16, 8 heads,
// 1024 sequences (hw). Block = 256 thr = 4 waves, 2 hw/block; wave handles
// (1 hw, 4 heads). S^T tiles: mfma(keys, queries) → C[key][query]; exp'd
// registers ARE the B-operand of O^T = V^T·P^T (C-layout ≡ B-layout), so P
// never moves. O^T C-layout gives float4 stores and the rowsum lands on the
// lane that needs it. Key 31 masked; Q row 31 zeroed. Gate column-sums fused
// (register → shfl over l → LDS → global atomic). In-place on q.
// ---------------------------------------------------------------------------
#define QS2 132   // row stride ushorts: 66 dw ≡ 2 mod 32
__global__ __launch_bounds__(256) void attn_spec_kernel(
    float* __restrict__ q, float* __restrict__ sums)
{
    __shared__ ushort Qs2[2][32 * QS2];   // 16.9 KB
    __shared__ float csum[CC];
    const int tid = threadIdx.x;
    const int hw0 = blockIdx.x * 2;
    if (tid < CC) csum[tid] = 0.f;

    for (int i = tid; i < 2 * 31 * 32; i += 256) {
        int hwl = (i >= 992) ? 1 : 0;
        int rem = i - hwl * 992;
        int dd = rem >> 5, c4 = rem & 31;
        float4 v = *(const float4*)&q[((size_t)dd * HWW + hw0 + hwl) * CC + c4 * 4];
        unsigned s0 = bf16rne(v.x), s1 = bf16rne(v.y);
        unsigned s2 = bf16rne(v.z), s3 = bf16rne(v.w);
        *(uint2*)&Qs2[hwl][dd * QS2 + c4 * 4] =
            make_uint2(s0 | (s1 << 16), s2 | (s3 << 16));
    }
    for (int i = tid; i < 2 * QS2; i += 256) {
        int hwl = i / QS2, c = i - hwl * QS2;
        Qs2[hwl][31 * QS2 + c] = 0;   // zero pad row 31
    }
    __syncthreads();

    const int lane = tid & 63;
    const int l    = lane & 15;
    const int quad = lane >> 4;
    const int wave = tid >> 6;
    const int hwl  = wave >> 1;
    const int hh   = (wave & 1) * 4;    // this wave's 4 heads
    const int hw   = hw0 + hwl;
    const ushort* Q = Qs2[hwl];
    const float k2 = SCALE2 * 1.44269504f;

    float osum[4][4];
#pragma unroll
    for (int a = 0; a < 4; ++a)
#pragma unroll
        for (int b = 0; b < 4; ++b) osum[a][b] = 0.f;

#pragma unroll
    for (int hl = 0; hl < 4; ++hl) {
        const int hc = (hh + hl) * HD;
        short4v qf[2];   // query/key frags (dual use: A for S, B for S)
        qf[0] = *(const short4v*)&Q[l * QS2 + hc + quad * 4];
        qf[1] = *(const short4v*)&Q[(16 + l) * QS2 + hc + quad * 4];
        short4v va[2];   // V^T A-frags: A[dd=l][key=quad*4+jj]
#pragma unroll
        for (int j = 0; j < 2; ++j)
#pragma unroll
            for (int jj = 0; jj < 4; ++jj)
                va[j][jj] = (short)Q[(j * 16 + quad * 4 + jj) * QS2 + hc + l];

        float4v o[2] = {(float4v){0.f,0.f,0.f,0.f}, (float4v){0.f,0.f,0.f,0.f}};
        float psum[2] = {0.f, 0.f};
#pragma unroll
        for (int j = 0; j < 2; ++j) {
#pragma unroll
            for (int i2 = 0; i2 < 2; ++i2) {
                float4v s = __builtin_amdgcn_mfma_f32_16x16x16bf16_1k(
                    qf[j], qf[i2], (float4v){0.f,0.f,0.f,0.f}, 0, 0, 0);
                unsigned u0 = __float_as_uint(__builtin_amdgcn_exp2f(s[0] * k2)) & 0xffff0000u;
                unsigned u1 = __float_as_uint(__builtin_amdgcn_exp2f(s[1] * k2)) & 0xffff0000u;
                unsigned u2 = __float_as_uint(__builtin_amdgcn_exp2f(s[2] * k2)) & 0xffff0000u;
                unsigned u3 = __float_as_uint(__builtin_amdgcn_exp2f(s[3] * k2)) & 0xffff0000u;
                if (j == 1 && quad == 3) u3 = 0;   // mask key 31 (P and rowsum)
                psum[i2] += (__uint_as_float(u0) + __uint_as_float(u1)) +
                            (__uint_as_float(u2) + __uint_as_float(u3));
                short4v pf;
                pf[0] = (short)(u0 >> 16); pf[1] = (short)(u1 >> 16);
                pf[2] = (short)(u2 >> 16); pf[3] = (short)(u3 >> 16);
                // O^T[dd][query] += V^T · P^T : exp'd C-regs ARE the B operand
                o[i2] = __builtin_amdgcn_mfma_f32_16x16x16bf16_1k(va[j], pf, o[i2], 0, 0, 0);
            }
        }
#pragma unroll
        for (int i2 = 0; i2 < 2; ++i2) {
            float a = psum[i2];
            a += __shfl_xor(a, 16);
            a += __shfl_xor(a, 32);          // rowsum(query = i2*16 + l), on this lane
            float inv = 1.f / a;
            int dq = i2 * 16 + l;
            if (dq < 31) {
                float4 ov = {o[i2][0]*inv, o[i2][1]*inv, o[i2][2]*inv, o[i2][3]*inv};
                *(float4*)&q[((size_t)dq * HWW + hw) * CC + hc + quad * 4] = ov;
#pragma unroll
                for (int r = 0; r < 4; ++r) osum[hl][r] += o[i2][r] * inv;
            }
        }
    }
    // gate sums: reduce over l (xor 1,2,4,8), then LDS, then one global atomic
#pragma unroll
    for (int hl = 0; hl < 4; ++hl)
#pragma unroll
        for (int r = 0; r < 4; ++r) {
            float v = osum[hl][r];
            v += __shfl_xor(v, 1); v += __shfl_xor(v, 2);
            v += __shfl_xor(v, 4); v += __shfl_xor(v, 8);
            if (l == 0) atomicAdd(&csum[(hh + hl) * HD + quad * 4 + r], v);
        }
    __syncthreads();
    if (tid < CC) atomicAdd(&sums[tid], csum[tid]);
}

// ---------------------------------------------------------------------------
// Kernel 3: spatial attention via bf16 MFMA (16x16x16), L=1024, d=16.
// S^T trick (A=keys, B=queries): C-layout == A-layout for the P·V MFMA.
// Queries pre-scaled by SCALE2*log2e. Conflict-free strides (proven r4).
// Gate column-sums fused. In-place on q.
// ---------------------------------------------------------------------------
#define QSS 20
#define QTP 1044
__global__ __launch_bounds__(512) void attn_spat_kernel(
    float* __restrict__ q, float* __restrict__ sums)
{
    __shared__ ushort Qs[HWW * QSS];   // 40 KB
    __shared__ ushort QTs[HD * QTP];   // 33.4 KB
    __shared__ float bsum[HD];
    const int tid = threadIdx.x;
    const int d   = blockIdx.x;
    const int h   = blockIdx.y;
    const size_t base = (size_t)d * HWW * CC + h * HD;
    if (tid < HD) bsum[tid] = 0.f;

    for (int i = tid; i < HWW * 4; i += 512) {
        int row = i >> 2, q4 = i & 3;
        float4 v = *(const float4*)&q[base + (size_t)row * CC + q4 * 4];
        unsigned s0 = bf16rne(v.x), s1 = bf16rne(v.y);
        unsigned s2 = bf16rne(v.z), s3 = bf16rne(v.w);
        *(uint2*)&Qs[row * QSS + q4 * 4] = make_uint2(s0 | (s1 << 16), s2 | (s3 << 16));
        QTs[(q4 * 4 + 0) * QTP + row] = (ushort)s0;
        QTs[(q4 * 4 + 1) * QTP + row] = (ushort)s1;
        QTs[(q4 * 4 + 2) * QTP + row] = (ushort)s2;
        QTs[(q4 * 4 + 3) * QTP + row] = (ushort)s3;
    }
    __syncthreads();

    const int lane = tid & 63;
    const int l    = lane & 15;
    const int quad = lane >> 4;
    const int Rw   = (tid >> 6) * 128;   // wave's query-row block
    const float k2 = SCALE2 * 1.44269504f;

    short4v qf[8];
#pragma unroll
    for (int lt = 0; lt < 8; ++lt) {
        short4v raw = *(short4v*)&Qs[(Rw + lt * 16 + l) * QSS + quad * 4];
        short4v sc;
#pragma unroll
        for (int e = 0; e < 4; ++e) {
            float f = bf2f((unsigned)(ushort)raw[e]) * k2;
            sc[e] = (short)bf16rne(f);
        }
        qf[lt] = sc;
    }

    float4v acc[8];
    float persum[8];
#pragma unroll
    for (int lt = 0; lt < 8; ++lt) {
        acc[lt] = (float4v){0.f, 0.f, 0.f, 0.f};
        persum[lt] = 0.f;
    }

#pragma unroll 2
    for (int mt = 0; mt < 64; ++mt) {
        const int m0 = mt * 16;
        short4v ka = *(short4v*)&Qs[(m0 + l) * QSS + quad * 4];
        short4v vb = *(short4v*)&QTs[l * QTP + m0 + quad * 4];
#pragma unroll
        for (int lt = 0; lt < 8; ++lt) {
            float4v s = __builtin_amdgcn_mfma_f32_16x16x16bf16_1k(
                ka, qf[lt], (float4v){0.f, 0.f, 0.f, 0.f}, 0, 0, 0);
            unsigned u0 = __float_as_uint(__builtin_amdgcn_exp2f(s[0])) & 0xffff0000u;
            unsigned u1 = __float_as_uint(__builtin_amdgcn_exp2f(s[1])) & 0xffff0000u;
            unsigned u2 = __float_as_uint(__builtin_amdgcn_exp2f(s[2])) & 0xffff0000u;
            unsigned u3 = __float_as_uint(__builtin_amdgcn_exp2f(s[3])) & 0xffff0000u;
            persum[lt] += (__uint_as_float(u0) + __uint_as_float(u1)) +
                          (__uint_as_float(u2) + __uint_as_float(u3));
            short4v pf;
            pf[0] = (short)(u0 >> 16); pf[1] = (short)(u1 >> 16);
            pf[2] = (short)(u2 >> 16); pf[3] = (short)(u3 >> 16);
            acc[lt] = __builtin_amdgcn_mfma_f32_16x16x16bf16_1k(pf, vb, acc[lt], 0, 0, 0);
        }
    }

    float osum = 0.f;   // this lane's channel (h*16 + l) partial column-sum
#pragma unroll
    for (int lt = 0; lt < 8; ++lt) {
        float a = persum[lt];
        a += __shfl_xor(a, 16);
        a += __shfl_xor(a, 32);
        float inv = 1.f / a;
#pragma unroll
        for (int reg = 0; reg < 4; ++reg) {
            float iv = __shfl(inv, quad * 4 + reg);
            int row = Rw + lt * 16 + quad * 4 + reg;
            float val = acc[lt][reg] * iv;
            q[base + (size_t)row * CC + l] = val;
            osum += val;
        }
    }
    osum += __shfl_xor(osum, 16);
    osum += __shfl_xor(osum, 32);
    if (quad == 0) atomicAdd(&bsum[l], osum);
    __syncthreads();
    if (tid < HD) atomicAdd(&sums[h * HD + tid], bsum[tid]);
}

// ---------------------------------------------------------------------------
// Kernel 4: gate. mean -> project through Wp (exact, by linearity) -> Wg -> sigmoid.
// ---------------------------------------------------------------------------
__global__ __launch_bounds__(128) void gate_kernel(
    const float* __restrict__ sums,
    const float* __restrict__ Wp1, const float* __restrict__ bp1,
    const float* __restrict__ Wp2, const float* __restrict__ bp2,
    const float* __restrict__ Wg,  const float* __restrict__ bg,
    float* __restrict__ gate)
{
    __shared__ float mean1[CC], mean2[CC], gi[2 * CC];
    const int c = threadIdx.x;
    const float invT = 1.f / (float)TOK;
    mean1[c] = sums[c] * invT;
    mean2[c] = sums[CC + c] * invT;
    __syncthreads();
    float a1 = bp1[c], a2 = bp2[c];
    for (int k = 0; k < CC; ++k) {
        a1 += mean1[k] * Wp1[k * CC + c];
        a2 += mean2[k] * Wp2[k * CC + c];
    }
    gi[c] = a1; gi[CC + c] = a2;
    __syncthreads();
    float g = bg[c];
    for (int j = 0; j < 2 * CC; ++j) g += gi[j] * Wg[j * CC + c];
    gate[c] = 1.f / (1.f + __expf(-g));
}

extern "C" void kernel_launch(void* const* d_in, const int* in_sizes, int n_in,
                              void* d_out, int out_size, void* d_ws, size_t ws_size,
                              hipStream_t stream)
{
    const float* x   = (const float*)d_in[0];
    const float* Wq1 = (const float*)d_in[1];
    const float* bq1 = (const float*)d_in[2];
    const float* Wp1 = (const float*)d_in[3];
    const float* bp1 = (const float*)d_in[4];
    const float* Wq2 = (const float*)d_in[5];
    const float* bq2 = (const float*)d_in[6];
    const float* Wp2 = (const float*)d_in[7];
    const float* bp2 = (const float*)d_in[8];
    const float* Wg  = (const float*)d_in[9];
    const float* bg  = (const float*)d_in[10];
    float* out = (float*)d_out;

    float* q1   = (float*)d_ws;                 // spec q / attn-out (in-place)
    float* q2   = q1 + (size_t)TOK * CC;        // spat q / attn-out (in-place)
    float* sums = q2 + (size_t)TOK * CC;        // 256 floats
    float* gate = sums + 2 * CC;                // 128 floats

    hipMemsetAsync(sums, 0, 2 * CC * sizeof(float), stream);
    mfma_proj_kernel<0><<<dim3(248), 512, 0, stream>>>(x, Wq1, bq1, nullptr, 0, q1);
    mfma_proj_kernel<0><<<dim3(248), 512, 0, stream>>>(x, Wq2, bq2, nullptr, 0, q2);
    attn_spec_kernel<<<dim3(512), 256, 0, stream>>>(q1, sums);
    attn_spat_kernel<<<dim3(DDIM, NH), 512, 0, stream>>>(q2, sums + CC);
    gate_kernel<<<1, 128, 0, stream>>>(sums, Wp1, bp1, Wp2, bp2, Wg, bg, gate);
    mfma_proj_kernel<1><<<dim3(248), 512, 0, stream>>>(q1, Wp1, bp1, gate, 0, out);
    mfma_proj_kernel<1><<<dim3(248), 512, 0, stream>>>(q2, Wp2, bp2, gate, 1, out);
}

// Round 6
// 221.061 us; speedup vs baseline: 2.8151x; 1.0983x over previous
//
#include <hip/hip_runtime.h>
#include <cstddef>

#define CC 128
#define NH 8
#define HD 16
#define DDIM 31
#define HWW 1024
#define TOK 31744   // DDIM * HWW
#define SCALE2 0.0625f   // (HD^-0.5)^2 — both QK^T operands pre-scaled in the ref

typedef __attribute__((ext_vector_type(4))) short  short4v;
typedef __attribute__((ext_vector_type(4))) float  float4v;

__device__ inline unsigned bf16rne(float f) {
    unsigned u = __float_as_uint(f);
    return (u + 0x7fffu + ((u >> 16) & 1u)) >> 16;
}
__device__ inline float bf2f(unsigned h) { return __uint_as_float(h << 16); }

// ---------------------------------------------------------------------------
// Kernel 0: one-time weight prep. For each of {Wq1,Wq2,Wp1,Wp2}: transpose to
// [co][k] and split into bf16 hi/lo planes in ws. Projection kernels then
// load W A-frags (b64) straight from L2-hot global — no W LDS, no per-block
// split VALU.
// ---------------------------------------------------------------------------
__global__ __launch_bounds__(256) void wsplit_kernel(
    const float* __restrict__ W0, const float* __restrict__ W1,
    const float* __restrict__ W2, const float* __restrict__ W3,
    ushort* __restrict__ wsp)
{
    const int mat = blockIdx.x >> 4;
    const int idx = ((blockIdx.x & 15) * 256 + threadIdx.x) * 4;  // k*128 + co
    const float* W = mat == 0 ? W0 : mat == 1 ? W1 : mat == 2 ? W2 : W3;
    ushort* hi = wsp + (size_t)mat * 2 * CC * CC;
    ushort* lo = hi + CC * CC;
    const int k  = idx >> 7;
    const int co = idx & 127;
    float4 w = *(const float4*)&W[idx];
    float wv[4] = {w.x, w.y, w.z, w.w};
#pragma unroll
    for (int e = 0; e < 4; ++e) {
        unsigned h = bf16rne(wv[e]);
        unsigned l = bf16rne(wv[e] - bf2f(h));
        hi[(co + e) * CC + k] = (ushort)h;
        lo[(co + e) * CC + k] = (ushort)l;
    }
}

// ---------------------------------------------------------------------------
// Kernel 1: Q projection, BOTH branches in one launch (blockIdx.y = branch).
// q_b[t][co] = sum_ci x[ci][t] * Wq_b[ci][co] + bq_b[co]
// W A-frags from pre-split global (registers); x staged transposed+split in
// LDS ([t][ci] hi/lo, 67.6 KB -> 2 blocks/CU). 3-term bf16x2 split.
// ---------------------------------------------------------------------------
#define AST 132   // LDS act row stride (ushorts): 66 dw ≡ 2 mod 32, b64 reads 2-way max
__global__ __launch_bounds__(512, 4) void qproj_kernel(
    const float* __restrict__ x, const ushort* __restrict__ wsp,
    const float* __restrict__ bq1, const float* __restrict__ bq2,
    float* __restrict__ q1, float* __restrict__ q2)
{
    __shared__ ushort Ahi[CC * AST], Alo[CC * AST];   // [t][ci], 67.6 KB
    const int tid    = threadIdx.x;
    const int t0     = blockIdx.x * 128;
    const int branch = blockIdx.y;
    const ushort* Whi = wsp + (size_t)branch * 2 * CC * CC;
    const ushort* Wlo = Whi + CC * CC;
    const float* bq  = branch ? bq2 : bq1;
    float* outp      = branch ? q2 : q1;

    const int lane = tid & 63;
    const int l    = lane & 15;
    const int quad = lane >> 4;
    const int co0  = (tid >> 6) * 16;   // wave owns 16 output channels

    // preload W frags to registers (global, L2-hot; independent of staging)
    short4v ah[8], al[8];
#pragma unroll
    for (int k8 = 0; k8 < 8; ++k8) {
        ah[k8] = *(const short4v*)&Whi[(co0 + l) * CC + k8 * 16 + quad * 4];
        al[k8] = *(const short4v*)&Wlo[(co0 + l) * CC + k8 * 16 + quad * 4];
    }

    // stage x tile transposed + split: [t][ci]
    for (int i = tid; i < CC * 128 / 4; i += 512) {
        int t4 = i & 31, ci = i >> 5;
        float4 v = *(const float4*)&x[(size_t)ci * TOK + t0 + t4 * 4];
        float xv[4] = {v.x, v.y, v.z, v.w};
#pragma unroll
        for (int e = 0; e < 4; ++e) {
            unsigned h = bf16rne(xv[e]);
            unsigned lw = bf16rne(xv[e] - bf2f(h));
            Ahi[(t4 * 4 + e) * AST + ci] = (ushort)h;
            Alo[(t4 * 4 + e) * AST + ci] = (ushort)lw;
        }
    }
    __syncthreads();

    float4v acc[8];
#pragma unroll
    for (int nt = 0; nt < 8; ++nt) acc[nt] = (float4v){0.f, 0.f, 0.f, 0.f};

#pragma unroll
    for (int k8 = 0; k8 < 8; ++k8) {
#pragma unroll
        for (int nt = 0; nt < 8; ++nt) {
            short4v bh = *(const short4v*)&Ahi[(nt * 16 + l) * AST + k8 * 16 + quad * 4];
            short4v bl = *(const short4v*)&Alo[(nt * 16 + l) * AST + k8 * 16 + quad * 4];
            acc[nt] = __builtin_amdgcn_mfma_f32_16x16x16bf16_1k(ah[k8], bh, acc[nt], 0, 0, 0);
            acc[nt] = __builtin_amdgcn_mfma_f32_16x16x16bf16_1k(ah[k8], bl, acc[nt], 0, 0, 0);
            acc[nt] = __builtin_amdgcn_mfma_f32_16x16x16bf16_1k(al[k8], bh, acc[nt], 0, 0, 0);
        }
    }

    float4 bv = *(const float4*)&bq[co0 + quad * 4];
    float bb[4] = {bv.x, bv.y, bv.z, bv.w};
#pragma unroll
    for (int nt = 0; nt < 8; ++nt) {
        int t = t0 + nt * 16 + l;
        float4 o = {acc[nt][0] + bb[0], acc[nt][1] + bb[1],
                    acc[nt][2] + bb[2], acc[nt][3] + bb[3]};
        *(float4*)&outp[(size_t)t * CC + co0 + quad * 4] = o;
    }
}

// ---------------------------------------------------------------------------
// Kernel 2: spectral attention via bf16 MFMA. L=31 (pad→32), d=16, 8 heads,
// 1024 sequences (hw). Block = 256 thr = 4 waves, 2 hw/block; wave handles
// (1 hw, 4 heads). S^T tiles; exp'd C-regs ARE the B-operand of O^T=V^T·P^T.
// Gate column-sums fused. In-place on q.
// ---------------------------------------------------------------------------
#define QS2 132
__global__ __launch_bounds__(256) void attn_spec_kernel(
    float* __restrict__ q, float* __restrict__ sums)
{
    __shared__ ushort Qs2[2][32 * QS2];   // 16.9 KB
    __shared__ float csum[CC];
    const int tid = threadIdx.x;
    const int hw0 = blockIdx.x * 2;
    if (tid < CC) csum[tid] = 0.f;

    for (int i = tid; i < 2 * 31 * 32; i += 256) {
        int hwl = (i >= 992) ? 1 : 0;
        int rem = i - hwl * 992;
        int dd = rem >> 5, c4 = rem & 31;
        float4 v = *(const float4*)&q[((size_t)dd * HWW + hw0 + hwl) * CC + c4 * 4];
        unsigned s0 = bf16rne(v.x), s1 = bf16rne(v.y);
        unsigned s2 = bf16rne(v.z), s3 = bf16rne(v.w);
        *(uint2*)&Qs2[hwl][dd * QS2 + c4 * 4] =
            make_uint2(s0 | (s1 << 16), s2 | (s3 << 16));
    }
    for (int i = tid; i < 2 * QS2; i += 256) {
        int hwl = i / QS2, c = i - hwl * QS2;
        Qs2[hwl][31 * QS2 + c] = 0;   // zero pad row 31
    }
    __syncthreads();

    const int lane = tid & 63;
    const int l    = lane & 15;
    const int quad = lane >> 4;
    const int wave = tid >> 6;
    const int hwl  = wave >> 1;
    const int hh   = (wave & 1) * 4;
    const int hw   = hw0 + hwl;
    const ushort* Q = Qs2[hwl];
    const float k2 = SCALE2 * 1.44269504f;

    float osum[4][4];
#pragma unroll
    for (int a = 0; a < 4; ++a)
#pragma unroll
        for (int b = 0; b < 4; ++b) osum[a][b] = 0.f;

#pragma unroll
    for (int hl = 0; hl < 4; ++hl) {
        const int hc = (hh + hl) * HD;
        short4v qf[2];
        qf[0] = *(const short4v*)&Q[l * QS2 + hc + quad * 4];
        qf[1] = *(const short4v*)&Q[(16 + l) * QS2 + hc + quad * 4];
        short4v va[2];
#pragma unroll
        for (int j = 0; j < 2; ++j)
#pragma unroll
            for (int jj = 0; jj < 4; ++jj)
                va[j][jj] = (short)Q[(j * 16 + quad * 4 + jj) * QS2 + hc + l];

        float4v o[2] = {(float4v){0.f,0.f,0.f,0.f}, (float4v){0.f,0.f,0.f,0.f}};
        float psum[2] = {0.f, 0.f};
#pragma unroll
        for (int j = 0; j < 2; ++j) {
#pragma unroll
            for (int i2 = 0; i2 < 2; ++i2) {
                float4v s = __builtin_amdgcn_mfma_f32_16x16x16bf16_1k(
                    qf[j], qf[i2], (float4v){0.f,0.f,0.f,0.f}, 0, 0, 0);
                unsigned u0 = __float_as_uint(__builtin_amdgcn_exp2f(s[0] * k2)) & 0xffff0000u;
                unsigned u1 = __float_as_uint(__builtin_amdgcn_exp2f(s[1] * k2)) & 0xffff0000u;
                unsigned u2 = __float_as_uint(__builtin_amdgcn_exp2f(s[2] * k2)) & 0xffff0000u;
                unsigned u3 = __float_as_uint(__builtin_amdgcn_exp2f(s[3] * k2)) & 0xffff0000u;
                if (j == 1 && quad == 3) u3 = 0;   // mask key 31
                psum[i2] += (__uint_as_float(u0) + __uint_as_float(u1)) +
                            (__uint_as_float(u2) + __uint_as_float(u3));
                short4v pf;
                pf[0] = (short)(u0 >> 16); pf[1] = (short)(u1 >> 16);
                pf[2] = (short)(u2 >> 16); pf[3] = (short)(u3 >> 16);
                o[i2] = __builtin_amdgcn_mfma_f32_16x16x16bf16_1k(va[j], pf, o[i2], 0, 0, 0);
            }
        }
#pragma unroll
        for (int i2 = 0; i2 < 2; ++i2) {
            float a = psum[i2];
            a += __shfl_xor(a, 16);
            a += __shfl_xor(a, 32);
            float inv = 1.f / a;
            int dq = i2 * 16 + l;
            if (dq < 31) {
                float4 ov = {o[i2][0]*inv, o[i2][1]*inv, o[i2][2]*inv, o[i2][3]*inv};
                *(float4*)&q[((size_t)dq * HWW + hw) * CC + hc + quad * 4] = ov;
#pragma unroll
                for (int r = 0; r < 4; ++r) osum[hl][r] += o[i2][r] * inv;
            }
        }
    }
#pragma unroll
    for (int hl = 0; hl < 4; ++hl)
#pragma unroll
        for (int r = 0; r < 4; ++r) {
            float v = osum[hl][r];
            v += __shfl_xor(v, 1); v += __shfl_xor(v, 2);
            v += __shfl_xor(v, 4); v += __shfl_xor(v, 8);
            if (l == 0) atomicAdd(&csum[(hh + hl) * HD + quad * 4 + r], v);
        }
    __syncthreads();
    if (tid < CC) atomicAdd(&sums[tid], csum[tid]);
}

// ---------------------------------------------------------------------------
// Kernel 3: spatial attention via bf16 MFMA, L=1024, d=16. Now 1024 threads =
// 16 waves/block (4 waves/SIMD — hides the exp→pack→MFMA chain); wave owns
// 64 query rows. Same proven numerics/strides as round 5. One block per
// (d,h) slice — in-place safe. Gate column-sums fused.
// ---------------------------------------------------------------------------
#define QSS 20
#define QTP 1044
__global__ __launch_bounds__(1024, 4) void attn_spat_kernel(
    float* __restrict__ q, float* __restrict__ sums)
{
    __shared__ ushort Qs[HWW * QSS];   // 40 KB
    __shared__ ushort QTs[HD * QTP];   // 33.4 KB
    __shared__ float bsum[HD];
    const int tid = threadIdx.x;
    const int d   = blockIdx.x;
    const int h   = blockIdx.y;
    const size_t base = (size_t)d * HWW * CC + h * HD;
    if (tid < HD) bsum[tid] = 0.f;

    for (int i = tid; i < HWW * 4; i += 1024) {
        int row = i >> 2, q4 = i & 3;
        float4 v = *(const float4*)&q[base + (size_t)row * CC + q4 * 4];
        unsigned s0 = bf16rne(v.x), s1 = bf16rne(v.y);
        unsigned s2 = bf16rne(v.z), s3 = bf16rne(v.w);
        *(uint2*)&Qs[row * QSS + q4 * 4] = make_uint2(s0 | (s1 << 16), s2 | (s3 << 16));
        QTs[(q4 * 4 + 0) * QTP + row] = (ushort)s0;
        QTs[(q4 * 4 + 1) * QTP + row] = (ushort)s1;
        QTs[(q4 * 4 + 2) * QTP + row] = (ushort)s2;
        QTs[(q4 * 4 + 3) * QTP + row] = (ushort)s3;
    }
    __syncthreads();

    const int lane = tid & 63;
    const int l    = lane & 15;
    const int quad = lane >> 4;
    const int Rw   = (tid >> 6) * 64;   // wave's 64-query-row block
    const float k2 = SCALE2 * 1.44269504f;

    short4v qf[4];
#pragma unroll
    for (int lt = 0; lt < 4; ++lt) {
        short4v raw = *(short4v*)&Qs[(Rw + lt * 16 + l) * QSS + quad * 4];
        short4v sc;
#pragma unroll
        for (int e = 0; e < 4; ++e) {
            float f = bf2f((unsigned)(ushort)raw[e]) * k2;
            sc[e] = (short)bf16rne(f);
        }
        qf[lt] = sc;
    }

    float4v acc[4];
    float persum[4];
#pragma unroll
    for (int lt = 0; lt < 4; ++lt) {
        acc[lt] = (float4v){0.f, 0.f, 0.f, 0.f};
        persum[lt] = 0.f;
    }

#pragma unroll 2
    for (int mt = 0; mt < 64; ++mt) {
        const int m0 = mt * 16;
        short4v ka = *(short4v*)&Qs[(m0 + l) * QSS + quad * 4];
        short4v vb = *(short4v*)&QTs[l * QTP + m0 + quad * 4];
#pragma unroll
        for (int lt = 0; lt < 4; ++lt) {
            float4v s = __builtin_amdgcn_mfma_f32_16x16x16bf16_1k(
                ka, qf[lt], (float4v){0.f, 0.f, 0.f, 0.f}, 0, 0, 0);
            unsigned u0 = __float_as_uint(__builtin_amdgcn_exp2f(s[0])) & 0xffff0000u;
            unsigned u1 = __float_as_uint(__builtin_amdgcn_exp2f(s[1])) & 0xffff0000u;
            unsigned u2 = __float_as_uint(__builtin_amdgcn_exp2f(s[2])) & 0xffff0000u;
            unsigned u3 = __float_as_uint(__builtin_amdgcn_exp2f(s[3])) & 0xffff0000u;
            persum[lt] += (__uint_as_float(u0) + __uint_as_float(u1)) +
                          (__uint_as_float(u2) + __uint_as_float(u3));
            short4v pf;
            pf[0] = (short)(u0 >> 16); pf[1] = (short)(u1 >> 16);
            pf[2] = (short)(u2 >> 16); pf[3] = (short)(u3 >> 16);
            acc[lt] = __builtin_amdgcn_mfma_f32_16x16x16bf16_1k(pf, vb, acc[lt], 0, 0, 0);
        }
    }

    float osum = 0.f;
#pragma unroll
    for (int lt = 0; lt < 4; ++lt) {
        float a = persum[lt];
        a += __shfl_xor(a, 16);
        a += __shfl_xor(a, 32);
        float inv = 1.f / a;
#pragma unroll
        for (int reg = 0; reg < 4; ++reg) {
            float iv = __shfl(inv, quad * 4 + reg);
            int row = Rw + lt * 16 + quad * 4 + reg;
            float val = acc[lt][reg] * iv;
            q[base + (size_t)row * CC + l] = val;
            osum += val;
        }
    }
    osum += __shfl_xor(osum, 16);
    osum += __shfl_xor(osum, 32);
    if (quad == 0) atomicAdd(&bsum[l], osum);
    __syncthreads();
    if (tid < HD) atomicAdd(&sums[h * HD + tid], bsum[tid]);
}

// ---------------------------------------------------------------------------
// Kernel 4: gate. mean -> project through Wp (exact, by linearity) -> Wg -> sigmoid.
// ---------------------------------------------------------------------------
__global__ __launch_bounds__(128) void gate_kernel(
    const float* __restrict__ sums,
    const float* __restrict__ Wp1, const float* __restrict__ bp1,
    const float* __restrict__ Wp2, const float* __restrict__ bp2,
    const float* __restrict__ Wg,  const float* __restrict__ bg,
    float* __restrict__ gate)
{
    __shared__ float mean1[CC], mean2[CC], gi[2 * CC];
    const int c = threadIdx.x;
    const float invT = 1.f / (float)TOK;
    mean1[c] = sums[c] * invT;
    mean2[c] = sums[CC + c] * invT;
    __syncthreads();
    float a1 = bp1[c], a2 = bp2[c];
    for (int k = 0; k < CC; ++k) {
        a1 += mean1[k] * Wp1[k * CC + c];
        a2 += mean2[k] * Wp2[k * CC + c];
    }
    gi[c] = a1; gi[CC + c] = a2;
    __syncthreads();
    float g = bg[c];
    for (int j = 0; j < 2 * CC; ++j) g += gi[j] * Wg[j * CC + c];
    gate[c] = 1.f / (1.f + __expf(-g));
}

// ---------------------------------------------------------------------------
// Kernel 5: output projection, BOTH branches per block, 64-token tiles.
// out[co][t] = g*(q1@Wp1 + bp1) + (1-g)*(q2@Wp2 + bp2) — single write, no
// read-modify-write ordering. W frags from pre-split global; A staged hi/lo
// in LDS (33.8 KB, reused across branches). Grid 496 -> 2 blocks/CU.
// ---------------------------------------------------------------------------
__global__ __launch_bounds__(512, 4) void oproj_kernel(
    const float* __restrict__ q1, const float* __restrict__ q2,
    const ushort* __restrict__ wsp,
    const float* __restrict__ bp1, const float* __restrict__ bp2,
    const float* __restrict__ gatev, float* __restrict__ out)
{
    __shared__ ushort Ahi[64 * AST], Alo[64 * AST];   // 33.8 KB
    const int tid = threadIdx.x;
    const int t0  = blockIdx.x * 64;
    const int lane = tid & 63;
    const int l    = lane & 15;
    const int quad = lane >> 4;
    const int co0  = (tid >> 6) * 16;

    float4v acc[2][4];
#pragma unroll
    for (int br = 0; br < 2; ++br)
#pragma unroll
        for (int nt = 0; nt < 4; ++nt) acc[br][nt] = (float4v){0.f, 0.f, 0.f, 0.f};

    for (int br = 0; br < 2; ++br) {
        const float* act = br ? q2 : q1;
        const ushort* Whi = wsp + (size_t)(2 + br) * 2 * CC * CC;
        const ushort* Wlo = Whi + CC * CC;

        short4v ah[8], al[8];
#pragma unroll
        for (int k8 = 0; k8 < 8; ++k8) {
            ah[k8] = *(const short4v*)&Whi[(co0 + l) * CC + k8 * 16 + quad * 4];
            al[k8] = *(const short4v*)&Wlo[(co0 + l) * CC + k8 * 16 + quad * 4];
        }

        __syncthreads();   // previous branch's LDS reads done
        for (int i = tid; i < 64 * CC / 4; i += 512) {
            int k4 = i & 31, t = i >> 5;
            float4 v = *(const float4*)&act[(size_t)(t0 + t) * CC + k4 * 4];
            float xv[4] = {v.x, v.y, v.z, v.w};
            unsigned hi[4], lo[4];
#pragma unroll
            for (int e = 0; e < 4; ++e) {
                hi[e] = bf16rne(xv[e]);
                lo[e] = bf16rne(xv[e] - bf2f(hi[e]));
            }
            *(uint2*)&Ahi[t * AST + k4 * 4] = make_uint2(hi[0] | (hi[1] << 16), hi[2] | (hi[3] << 16));
            *(uint2*)&Alo[t * AST + k4 * 4] = make_uint2(lo[0] | (lo[1] << 16), lo[2] | (lo[3] << 16));
        }
        __syncthreads();

#pragma unroll
        for (int k8 = 0; k8 < 8; ++k8) {
#pragma unroll
            for (int nt = 0; nt < 4; ++nt) {
                short4v bh = *(const short4v*)&Ahi[(nt * 16 + l) * AST + k8 * 16 + quad * 4];
                short4v bl = *(const short4v*)&Alo[(nt * 16 + l) * AST + k8 * 16 + quad * 4];
                acc[br][nt] = __builtin_amdgcn_mfma_f32_16x16x16bf16_1k(ah[k8], bh, acc[br][nt], 0, 0, 0);
                acc[br][nt] = __builtin_amdgcn_mfma_f32_16x16x16bf16_1k(ah[k8], bl, acc[br][nt], 0, 0, 0);
                acc[br][nt] = __builtin_amdgcn_mfma_f32_16x16x16bf16_1k(al[k8], bh, acc[br][nt], 0, 0, 0);
            }
        }
    }

    float4 b1 = *(const float4*)&bp1[co0 + quad * 4];
    float4 b2 = *(const float4*)&bp2[co0 + quad * 4];
    float4 gv = *(const float4*)&gatev[co0 + quad * 4];
    float bb1[4] = {b1.x, b1.y, b1.z, b1.w};
    float bb2[4] = {b2.x, b2.y, b2.z, b2.w};
    float gg[4]  = {gv.x, gv.y, gv.z, gv.w};
#pragma unroll
    for (int nt = 0; nt < 4; ++nt) {
        int t = t0 + nt * 16 + l;
#pragma unroll
        for (int reg = 0; reg < 4; ++reg) {
            size_t idx = (size_t)(co0 + quad * 4 + reg) * TOK + t;
            out[idx] = gg[reg] * (acc[0][nt][reg] + bb1[reg]) +
                       (1.f - gg[reg]) * (acc[1][nt][reg] + bb2[reg]);
        }
    }
}

extern "C" void kernel_launch(void* const* d_in, const int* in_sizes, int n_in,
                              void* d_out, int out_size, void* d_ws, size_t ws_size,
                              hipStream_t stream)
{
    const float* x   = (const float*)d_in[0];
    const float* Wq1 = (const float*)d_in[1];
    const float* bq1 = (const float*)d_in[2];
    const float* Wp1 = (const float*)d_in[3];
    const float* bp1 = (const float*)d_in[4];
    const float* Wq2 = (const float*)d_in[5];
    const float* bq2 = (const float*)d_in[6];
    const float* Wp2 = (const float*)d_in[7];
    const float* bp2 = (const float*)d_in[8];
    const float* Wg  = (const float*)d_in[9];
    const float* bg  = (const float*)d_in[10];
    float* out = (float*)d_out;

    float* q1    = (float*)d_ws;                 // spec q / attn-out (in-place)
    float* q2    = q1 + (size_t)TOK * CC;        // spat q / attn-out (in-place)
    float* sums  = q2 + (size_t)TOK * CC;        // 256 floats
    float* gate  = sums + 2 * CC;                // 128 floats
    ushort* wsp  = (ushort*)(gate + CC);         // 4 x 2 x 128 x 128 ushorts (256 KB)

    hipMemsetAsync(sums, 0, 2 * CC * sizeof(float), stream);
    wsplit_kernel<<<dim3(64), 256, 0, stream>>>(Wq1, Wq2, Wp1, Wp2, wsp);
    qproj_kernel<<<dim3(248, 2), 512, 0, stream>>>(x, wsp, bq1, bq2, q1, q2);
    attn_spec_kernel<<<dim3(512), 256, 0, stream>>>(q1, sums);
    attn_spat_kernel<<<dim3(DDIM, NH), 1024, 0, stream>>>(q2, sums + CC);
    gate_kernel<<<1, 128, 0, stream>>>(sums, Wp1, bp1, Wp2, bp2, Wg, bg, gate);
    oproj_kernel<<<dim3(496), 512, 0, stream>>>(q1, q2, wsp, bp1, bp2, gate, out);
}